// Round 1
// baseline (531.496 us; speedup 1.0000x reference)
//
#include <hip/hip_runtime.h>
#include <hip/hip_bf16.h>

// Swin block on MI355X. Round 0: correctness-first bf16-MFMA pipeline.
// Layouts: activations token-major bf16 ("B^T" GEMM form), weights bf16 row-major.
// ws layout (bytes):
//   bufA  @ 0          : 38,535,168  (xn_t / attn_out_t / xn2_t  [50176][384] bf16)
//   bufB  @ 38535168   : 115,605,504 (qkv_t [50176][1152] bf16; later h_t [50176][768])
//   be    @ 153,  ...  : 98,304      (bias expanded [6][64][64] f32)
//   wbf   @ +98304     : 3,538,944   (all weights as bf16)
// total 157,777,920 B

typedef __bf16 bf16x8 __attribute__((ext_vector_type(8)));
typedef __bf16 bf16x4 __attribute__((ext_vector_type(4)));
typedef float  f32x4  __attribute__((ext_vector_type(4)));

#define GAS __attribute__((address_space(1)))
#define LAS __attribute__((address_space(3)))

__device__ __forceinline__ void gload_lds16(const void* g, void* l) {
  __builtin_amdgcn_global_load_lds((const GAS void*)g, (LAS void*)l, 16, 0, 0);
}

__device__ __forceinline__ int div7u(int m) { return (m * 37) >> 8; }  // valid m<56

// ---------------- fp32 -> bf16 weight convert ----------------
__global__ __launch_bounds__(256) void cvt_bf16_kernel(const float* __restrict__ src,
                                                       __bf16* __restrict__ dst, int n) {
  int i = blockIdx.x * 256 + threadIdx.x;
  if (i < n) dst[i] = (__bf16)src[i];
}

// ---------------- relative-position bias expand: [6][64][64] ----------------
__global__ __launch_bounds__(256) void bias_expand_kernel(const float* __restrict__ tbl,
                                                          float* __restrict__ be) {
  int idx = blockIdx.x * 256 + threadIdx.x;
  if (idx >= 6 * 64 * 64) return;
  int m = idx & 63, n = (idx >> 6) & 63, h = idx >> 12;
  float v = 0.f;
  if (m < 49 && n < 49) {
    int in_ = div7u(n), jn = n - in_ * 7;
    int im  = div7u(m), jm = m - im * 7;
    int t = (in_ - im + 6) * 13 + (jn - jm + 6);
    v = tbl[t * 6 + h];
  }
  be[idx] = v;
}

// ---------------- LayerNorm(channel) + transpose to token-major bf16 ----------------
// x: [64][384][784] f32 (LN over the 384 channels per position, ddof=1), out: [50176][384] bf16
__global__ __launch_bounds__(256) void ln_t_kernel(const float* __restrict__ x,
                                                   const float* __restrict__ gw,
                                                   const float* __restrict__ gb,
                                                   __bf16* __restrict__ out) {
  const int tid = threadIdx.x;
  const int tok0 = blockIdx.x << 8;
  const int tok = tok0 + tid;
  const unsigned b = (unsigned)tok / 784u;
  const unsigned p = (unsigned)tok - b * 784u;
  const float* xp = x + (size_t)b * (384u * 784u) + p;
  float s = 0.f, s2 = 0.f;
  for (int c = 0; c < 384; ++c) { float v = xp[c * 784]; s += v; s2 += v * v; }
  float mean = s * (1.f / 384.f);
  float var  = (s2 - s * mean) * (1.f / 383.f);   // unbiased (ddof=1)
  float rstd = rsqrtf(var + 1e-5f);
  __shared__ __align__(16) __bf16 tile[256][40];  // 32 c-chunk, pad->40 (16B rows)
  for (int cc = 0; cc < 384; cc += 32) {
    __syncthreads();
    #pragma unroll
    for (int it = 0; it < 32; ++it) {
      float v = xp[(cc + it) * 784];
      tile[tid][it] = (__bf16)((v - mean) * rstd * gw[cc + it] + gb[cc + it]);
    }
    __syncthreads();
    #pragma unroll
    for (int j = 0; j < 4; ++j) {
      int id = (j << 8) + tid;
      int tl = id >> 2, c8 = (id & 3) << 3;
      bf16x8 v = *(const bf16x8*)(&tile[tl][c8]);
      *(bf16x8*)(out + (size_t)(tok0 + tl) * 384 + cc + c8) = v;
    }
  }
}

// ---------------- GEMM: C[m][tok] = sum_k A[m][k] * Bt[tok][k] ----------------
// m97-style: 128x128 tile, BK=64, 4 waves (2x2), global_load_lds w16, XOR-swizzled LDS.
// EPI 0: transpose-epilogue -> bf16 outT[tok][ldo] at column ocol+m
// EPI 1: same + exact GELU
// EPI 2: fp32 channel-major outR[b][o][p] = resid + acc   (Cout=384)
template <int EPI>
__global__ __launch_bounds__(256, 2) void gemm_bt(const __bf16* __restrict__ A, int lda,
                                                  const __bf16* __restrict__ Bt, int ldb,
                                                  int K,
                                                  __bf16* __restrict__ outT, int ldo, int ocol,
                                                  float* __restrict__ outR,
                                                  const float* __restrict__ resid) {
  __shared__ __align__(16) char smem[33792];  // staging 2x16KB; transpose 128x264B
  const int tid = threadIdx.x;
  const int lane = tid & 63;
  const int w = tid >> 6;
  const int wr = w >> 1, wc = w & 1;
  const int c = lane & 15, g = lane >> 4;
  const int m0 = blockIdx.y << 7;
  const int n0 = blockIdx.x << 7;
  f32x4 acc[4][4] = {};
  for (int k0 = 0; k0 < K; k0 += 64) {
    __syncthreads();
    #pragma unroll
    for (int i = 0; i < 4; ++i) {
      int s = (i << 8) + tid;
      int row = s >> 3;
      int kk = ((s ^ row) & 7) << 3;  // pre-swizzled global source -> linear LDS dest
      gload_lds16(A  + (size_t)(m0 + row) * lda + (k0 + kk), smem + ((i << 8) + (w << 6)) * 16);
      gload_lds16(Bt + (size_t)(n0 + row) * ldb + (k0 + kk), smem + 16384 + ((i << 8) + (w << 6)) * 16);
    }
    asm volatile("s_waitcnt vmcnt(0)" ::: "memory");
    __syncthreads();
    #pragma unroll
    for (int ks = 0; ks < 2; ++ks) {
      bf16x8 af[4], bfv[4];
      #pragma unroll
      for (int mi = 0; mi < 4; ++mi) {
        int r = (wr << 6) + (mi << 4) + c;
        af[mi] = *(const bf16x8*)(smem + (r << 7) + (((ks << 6) + (g << 4)) ^ ((r & 7) << 4)));
      }
      #pragma unroll
      for (int nj = 0; nj < 4; ++nj) {
        int r = (wc << 6) + (nj << 4) + c;
        bfv[nj] = *(const bf16x8*)(smem + 16384 + (r << 7) + (((ks << 6) + (g << 4)) ^ ((r & 7) << 4)));
      }
      #pragma unroll
      for (int mi = 0; mi < 4; ++mi)
        #pragma unroll
        for (int nj = 0; nj < 4; ++nj)
          acc[mi][nj] = __builtin_amdgcn_mfma_f32_16x16x32_bf16(af[mi], bfv[nj], acc[mi][nj], 0, 0, 0);
    }
  }
  if constexpr (EPI <= 1) {
    __syncthreads();
    #pragma unroll
    for (int mi = 0; mi < 4; ++mi)
      #pragma unroll
      for (int nj = 0; nj < 4; ++nj) {
        f32x4 v = acc[mi][nj];
        if constexpr (EPI == 1) {
          #pragma unroll
          for (int r = 0; r < 4; ++r)
            v[r] = 0.5f * v[r] * (1.f + erff(v[r] * 0.70710678f));
        }
        bf16x4 pk = {(__bf16)v[0], (__bf16)v[1], (__bf16)v[2], (__bf16)v[3]};
        int nl = (wc << 6) + (nj << 4) + c;            // token-local
        int ml = (wr << 6) + (mi << 4) + (g << 2);     // m-local (4 consecutive via regs)
        *(bf16x4*)(smem + nl * 264 + ml * 2) = pk;     // [128][132] bf16
      }
    __syncthreads();
    #pragma unroll
    for (int it = 0; it < 8; ++it) {
      int id = (it << 8) + tid;
      int n = id >> 4, mc = id & 15;
      bf16x8 v = *(const bf16x8*)(smem + n * 264 + (mc << 4));
      *(bf16x8*)(outT + (size_t)(n0 + n) * ldo + (ocol + m0 + (mc << 3))) = v;
    }
  } else {
    #pragma unroll
    for (int nj = 0; nj < 4; ++nj) {
      int tokn = n0 + (wc << 6) + (nj << 4) + c;
      unsigned bb = (unsigned)tokn / 784u;
      unsigned pp = (unsigned)tokn - bb * 784u;
      size_t base = (size_t)bb * (384u * 784u) + pp;
      #pragma unroll
      for (int mi = 0; mi < 4; ++mi) {
        int o = m0 + (wr << 6) + (mi << 4) + (g << 2);
        #pragma unroll
        for (int r = 0; r < 4; ++r) {
          size_t a2 = base + (size_t)(o + r) * 784u;
          outR[a2] = resid[a2] + acc[mi][nj][r];
        }
      }
    }
  }
}

// ---------------- windowed attention: 1 wave per (window, head) ----------------
// qkv: [50176][1152] bf16 token-major (o = qi*384 + h*64 + d), out: [50176][384] bf16.
// S^T = mfma(K,Q); softmax over rows (keys) via shfl_xor(16/32); P,V^T staged in LDS.
__global__ __launch_bounds__(256, 2) void attn_kernel(const __bf16* __restrict__ qkv,
                                                      const float* __restrict__ be,
                                                      __bf16* __restrict__ outt) {
  __shared__ __align__(16) char smem_all[4][16384];  // per-wave: K|Q then VT|P (aliased)
  const int tid = threadIdx.x;
  const int lane = tid & 63;
  const int w = tid >> 6;
  char* sm = (char*)smem_all[w];
  const int pair = blockIdx.x * 4 + w;               // 6144 pairs
  const int h = pair % 6;
  const int wg = pair / 6;
  const int b = wg >> 4;
  const int wi = wg & 15;
  const int wh = wi >> 2, wwi = wi & 3;
  const int cc = lane & 15, g = lane >> 4;

  // ---- stage K (sm 0..8K) and Q (8K..16K): 64 rows x 64 d, XOR-swizzled via source ----
  {
    int rsub = lane >> 3;
    int slot = lane & 7;
    int dc = (slot ^ rsub) << 3;
    #pragma unroll
    for (int i = 0; i < 8; ++i) {
      int r = i * 8 + rsub;
      int m = r < 49 ? r : 48;                       // clamp pad rows (masked later)
      int im = div7u(m), jm = m - im * 7;
      int sh = wh * 7 + im + 3; if (sh >= 28) sh -= 28;   // unshift gather
      int sw = wwi * 7 + jm + 3; if (sw >= 28) sw -= 28;
      size_t trow = (size_t)(b * 784 + sh * 28 + sw) * 1152;
      gload_lds16(qkv + trow + 384 + h * 64 + dc, sm + i * 1024);         // K
      gload_lds16(qkv + trow +       h * 64 + dc, sm + 8192 + i * 1024);  // Q
    }
  }
  asm volatile("s_waitcnt vmcnt(0)" ::: "memory");
  __syncthreads();

  // ---- S^T = K @ Q^T  (rows m = keys, cols n = queries) ----
  f32x4 sacc[4][4] = {};
  #pragma unroll
  for (int ks = 0; ks < 2; ++ks) {
    bf16x8 kf[4], qf[4];
    #pragma unroll
    for (int mi = 0; mi < 4; ++mi) {
      int r = (mi << 4) + cc;
      kf[mi] = *(const bf16x8*)(sm + (r << 7) + (((ks << 6) + (g << 4)) ^ ((r & 7) << 4)));
    }
    #pragma unroll
    for (int nj = 0; nj < 4; ++nj) {
      int r = (nj << 4) + cc;
      qf[nj] = *(const bf16x8*)(sm + 8192 + (r << 7) + (((ks << 6) + (g << 4)) ^ ((r & 7) << 4)));
    }
    #pragma unroll
    for (int mi = 0; mi < 4; ++mi)
      #pragma unroll
      for (int nj = 0; nj < 4; ++nj)
        sacc[mi][nj] = __builtin_amdgcn_mfma_f32_16x16x32_bf16(kf[mi], qf[nj], sacc[mi][nj], 0, 0, 0);
  }
  __syncthreads();

  // shift-region id (for the -100 mask) for this lane's 16 m values
  int r9m[4][4];
  #pragma unroll
  for (int mi = 0; mi < 4; ++mi)
    #pragma unroll
    for (int rr = 0; rr < 4; ++rr) {
      int m = (mi << 4) + (g << 2) + rr; if (m > 48) m = 48;
      int im = div7u(m), jm = m - im * 7;
      int sh = wh * 7 + im, sw = wwi * 7 + jm;
      r9m[mi][rr] = ((sh < 21) ? 0 : (sh < 25 ? 1 : 2)) * 3 + ((sw < 21) ? 0 : (sw < 25 ? 1 : 2));
    }

  // ---- softmax over m (rows of S^T) + write P^T -> P_lds[n][m] (sm+8192, swizzled) ----
  #pragma unroll
  for (int nj = 0; nj < 4; ++nj) {
    int n = (nj << 4) + cc;
    int ncl = n > 48 ? 48 : n;
    int in_ = div7u(ncl), jn = ncl - in_ * 7;
    int shn = wh * 7 + in_, swn = wwi * 7 + jn;
    int r9n = ((shn < 21) ? 0 : (shn < 25 ? 1 : 2)) * 3 + ((swn < 21) ? 0 : (swn < 25 ? 1 : 2));
    float mx = -1e30f;
    #pragma unroll
    for (int mi = 0; mi < 4; ++mi) {
      f32x4 bia = *(const f32x4*)(be + (((h << 6) + n) << 6) + (mi << 4) + (g << 2));
      #pragma unroll
      for (int rr = 0; rr < 4; ++rr) {
        int m = (mi << 4) + (g << 2) + rr;
        float t = (m < 49)
            ? sacc[mi][nj][rr] * 0.125f + bia[rr] + ((r9m[mi][rr] == r9n) ? 0.f : -100.f)
            : -1e30f;
        sacc[mi][nj][rr] = t;
        mx = fmaxf(mx, t);
      }
    }
    mx = fmaxf(mx, __shfl_xor(mx, 16, 64));
    mx = fmaxf(mx, __shfl_xor(mx, 32, 64));
    float sum = 0.f;
    #pragma unroll
    for (int mi = 0; mi < 4; ++mi)
      #pragma unroll
      for (int rr = 0; rr < 4; ++rr) {
        float e = __expf(sacc[mi][nj][rr] - mx);
        sacc[mi][nj][rr] = e;
        sum += e;
      }
    sum += __shfl_xor(sum, 16, 64);
    sum += __shfl_xor(sum, 32, 64);
    float inv = __builtin_amdgcn_rcpf(sum);
    #pragma unroll
    for (int mi = 0; mi < 4; ++mi) {
      bf16x4 pk = {(__bf16)(sacc[mi][nj][0] * inv), (__bf16)(sacc[mi][nj][1] * inv),
                   (__bf16)(sacc[mi][nj][2] * inv), (__bf16)(sacc[mi][nj][3] * inv)};
      *(bf16x4*)(sm + 8192 + (n << 7) + (((mi << 5) + (g << 3)) ^ ((n & 7) << 4))) = pk;
    }
  }

  // ---- stage V^T -> sm[0..8K): VT[d][m], chunk-XOR swizzle ((m>>3)^(d&7)) ----
  {
    int ml = lane & 15, dq = lane >> 4;
    #pragma unroll
    for (int it = 0; it < 4; ++it) {
      int m = (it << 4) + ml;
      int mc_ = m > 48 ? 48 : m;
      int im = div7u(mc_), jm = mc_ - im * 7;
      int sh = wh * 7 + im + 3; if (sh >= 28) sh -= 28;
      int sw = wwi * 7 + jm + 3; if (sw >= 28) sw -= 28;
      const __bf16* gv = qkv + (size_t)(b * 784 + sh * 28 + sw) * 1152 + 768 + h * 64;
      #pragma unroll
      for (int hd = 0; hd < 2; ++hd) {
        int dbase = (hd << 5) + (dq << 3);
        bf16x8 v = *(const bf16x8*)(gv + dbase);
        #pragma unroll
        for (int j = 0; j < 8; ++j) {
          int d = dbase + j;
          *(__bf16*)(sm + (d << 7) + ((((m >> 3) ^ (d & 7)) << 4) + ((m & 7) << 1))) = v[j];
        }
      }
    }
  }
  __syncthreads();

  // ---- O[n][d] = P @ V ----
  f32x4 oacc[4][4] = {};
  #pragma unroll
  for (int ks = 0; ks < 2; ++ks) {
    bf16x8 pf[4], vf[4];
    #pragma unroll
    for (int ni = 0; ni < 4; ++ni) {
      int n = (ni << 4) + cc;
      pf[ni] = *(const bf16x8*)(sm + 8192 + (n << 7) + (((ks << 6) + (g << 4)) ^ ((n & 7) << 4)));
    }
    #pragma unroll
    for (int dj = 0; dj < 4; ++dj) {
      int d = (dj << 4) + cc;
      vf[dj] = *(const bf16x8*)(sm + (d << 7) + ((((ks << 2) + g) ^ (d & 7)) << 4));
    }
    #pragma unroll
    for (int ni = 0; ni < 4; ++ni)
      #pragma unroll
      for (int dj = 0; dj < 4; ++dj)
        oacc[ni][dj] = __builtin_amdgcn_mfma_f32_16x16x32_bf16(pf[ni], vf[dj], oacc[ni][dj], 0, 0, 0);
  }

  // ---- scatter O back to unshifted token-major layout ----
  #pragma unroll
  for (int ni = 0; ni < 4; ++ni)
    #pragma unroll
    for (int rr = 0; rr < 4; ++rr) {
      int n = (ni << 4) + (g << 2) + rr;
      if (n < 49) {
        int im = div7u(n), jn = n - im * 7;
        int sh = wh * 7 + im + 3; if (sh >= 28) sh -= 28;
        int sw = wwi * 7 + jn + 3; if (sw >= 28) sw -= 28;
        __bf16* op = outt + (size_t)(b * 784 + sh * 28 + sw) * 384 + h * 64;
        #pragma unroll
        for (int dj = 0; dj < 4; ++dj)
          op[(dj << 4) + cc] = (__bf16)oacc[ni][dj][rr];
      }
    }
}

// ---------------- host launcher ----------------
extern "C" void kernel_launch(void* const* d_in, const int* in_sizes, int n_in,
                              void* d_out, int out_size, void* d_ws, size_t ws_size,
                              hipStream_t stream) {
  (void)in_sizes; (void)n_in; (void)out_size; (void)ws_size;
  const float* x     = (const float*)d_in[0];
  const float* n1w   = (const float*)d_in[1];
  const float* n1b   = (const float*)d_in[2];
  const float* qkvw  = (const float*)d_in[3];
  const float* tbl   = (const float*)d_in[4];
  const float* projw = (const float*)d_in[5];
  const float* n2w   = (const float*)d_in[6];
  const float* n2b   = (const float*)d_in[7];
  const float* w1    = (const float*)d_in[8];
  const float* w3    = (const float*)d_in[9];
  float* out = (float*)d_out;

  char* ws = (char*)d_ws;
  __bf16* bufA = (__bf16*)ws;                               // 38,535,168 B
  __bf16* bufB = (__bf16*)(ws + 38535168);                  // 115,605,504 B
  float*  be   = (float*)(ws + 154140672);                  // 98,304 B
  __bf16* wq   = (__bf16*)(ws + 154238976);
  __bf16* wp   = wq + 442368;
  __bf16* wm1  = wp + 147456;
  __bf16* wm3  = wm1 + 589824;

  cvt_bf16_kernel<<<(442368 + 255) / 256, 256, 0, stream>>>(qkvw, wq, 442368);
  cvt_bf16_kernel<<<(147456 + 255) / 256, 256, 0, stream>>>(projw, wp, 147456);
  cvt_bf16_kernel<<<(589824 + 255) / 256, 256, 0, stream>>>(w1, wm1, 589824);
  cvt_bf16_kernel<<<(589824 + 255) / 256, 256, 0, stream>>>(w3, wm3, 589824);
  bias_expand_kernel<<<96, 256, 0, stream>>>(tbl, be);

  // LN1 -> xn_t (bufA)
  ln_t_kernel<<<196, 256, 0, stream>>>(x, n1w, n1b, bufA);
  // qkv: [1152x384] @ xn_t -> qkv_t (bufB, token-major)
  gemm_bt<0><<<dim3(392, 9), 256, 0, stream>>>(wq, 384, bufA, 384, 384, bufB, 1152, 0, nullptr, nullptr);
  // attention -> attn_out_t (bufA)
  attn_kernel<<<1536, 256, 0, stream>>>(bufB, be, bufA);
  // proj + residual(x) -> d_out (fp32 channel-major)
  gemm_bt<2><<<dim3(392, 3), 256, 0, stream>>>(wp, 384, bufA, 384, 384, nullptr, 0, 0, out, x);
  // LN2 -> xn2_t (bufA)
  ln_t_kernel<<<196, 256, 0, stream>>>(out, n2w, n2b, bufA);
  // MLP split into two HID halves (h_t reuses bufB, [50176][768])
  for (int pass = 0; pass < 2; ++pass) {
    gemm_bt<1><<<dim3(392, 6), 256, 0, stream>>>(wm1 + (size_t)pass * 768 * 384, 384, bufA, 384, 384,
                                                 bufB, 768, 0, nullptr, nullptr);
    gemm_bt<2><<<dim3(392, 3), 256, 0, stream>>>(wm3 + pass * 768, 1536, bufB, 768, 768,
                                                 nullptr, 0, 0, out, out);
  }
}

// Round 2
// 497.602 us; speedup vs baseline: 1.0681x; 1.0681x over previous
//
#include <hip/hip_runtime.h>
#include <hip/hip_bf16.h>

// Swin block on MI355X. Round 2: pipelined (dbuf+prefetch) GEMM, XCD-chunked
// block swizzle with y-fast decode (panel L2 reuse), float4 EPI2 epilogue via
// swapped-operand MFMA, merged weight-convert.
// ws layout unchanged from round 0/1.

typedef __bf16 bf16x8 __attribute__((ext_vector_type(8)));
typedef __bf16 bf16x4 __attribute__((ext_vector_type(4)));
typedef float  f32x4  __attribute__((ext_vector_type(4)));

#define GAS __attribute__((address_space(1)))
#define LAS __attribute__((address_space(3)))

__device__ __forceinline__ void gload_lds16(const void* g, void* l) {
  __builtin_amdgcn_global_load_lds((const GAS void*)g, (LAS void*)l, 16, 0, 0);
}

__device__ __forceinline__ int div7u(int m) { return (m * 37) >> 8; }  // valid m<56

// ---------------- fp32 -> bf16 weight convert (all four weights, one launch) ----------------
__global__ __launch_bounds__(256) void cvt_all_kernel(const float* __restrict__ s0,
                                                      const float* __restrict__ s1,
                                                      const float* __restrict__ s2,
                                                      const float* __restrict__ s3,
                                                      __bf16* __restrict__ d0,
                                                      __bf16* __restrict__ d1,
                                                      __bf16* __restrict__ d2,
                                                      __bf16* __restrict__ d3) {
  int i = blockIdx.x * 256 + threadIdx.x;
  if (i < 442368) { d0[i] = (__bf16)s0[i]; return; }
  i -= 442368;
  if (i < 147456) { d1[i] = (__bf16)s1[i]; return; }
  i -= 147456;
  if (i < 589824) { d2[i] = (__bf16)s2[i]; return; }
  i -= 589824;
  d3[i] = (__bf16)s3[i];
}

// ---------------- relative-position bias expand: [6][64][64] ----------------
__global__ __launch_bounds__(256) void bias_expand_kernel(const float* __restrict__ tbl,
                                                          float* __restrict__ be) {
  int idx = blockIdx.x * 256 + threadIdx.x;
  if (idx >= 6 * 64 * 64) return;
  int m = idx & 63, n = (idx >> 6) & 63, h = idx >> 12;
  float v = 0.f;
  if (m < 49 && n < 49) {
    int in_ = div7u(n), jn = n - in_ * 7;
    int im  = div7u(m), jm = m - im * 7;
    int t = (in_ - im + 6) * 13 + (jn - jm + 6);
    v = tbl[t * 6 + h];
  }
  be[idx] = v;
}

// ---------------- LayerNorm(channel) + transpose to token-major bf16 ----------------
__global__ __launch_bounds__(256) void ln_t_kernel(const float* __restrict__ x,
                                                   const float* __restrict__ gw,
                                                   const float* __restrict__ gb,
                                                   __bf16* __restrict__ out) {
  const int tid = threadIdx.x;
  const int tok0 = blockIdx.x << 8;
  const int tok = tok0 + tid;
  const unsigned b = (unsigned)tok / 784u;
  const unsigned p = (unsigned)tok - b * 784u;
  const float* xp = x + (size_t)b * (384u * 784u) + p;
  float s = 0.f, s2 = 0.f;
  for (int c = 0; c < 384; ++c) { float v = xp[c * 784]; s += v; s2 += v * v; }
  float mean = s * (1.f / 384.f);
  float var  = (s2 - s * mean) * (1.f / 383.f);   // unbiased (ddof=1)
  float rstd = rsqrtf(var + 1e-5f);
  __shared__ __align__(16) __bf16 tile[256][40];
  for (int cc = 0; cc < 384; cc += 32) {
    __syncthreads();
    #pragma unroll
    for (int it = 0; it < 32; ++it) {
      float v = xp[(cc + it) * 784];
      tile[tid][it] = (__bf16)((v - mean) * rstd * gw[cc + it] + gb[cc + it]);
    }
    __syncthreads();
    #pragma unroll
    for (int j = 0; j < 4; ++j) {
      int id = (j << 8) + tid;
      int tl = id >> 2, c8 = (id & 3) << 3;
      bf16x8 v = *(const bf16x8*)(&tile[tl][c8]);
      *(bf16x8*)(out + (size_t)(tok0 + tl) * 384 + cc + c8) = v;
    }
  }
}

// ---------------- GEMM: C[m][tok] = sum_k A[m][k] * Bt[tok][k] ----------------
// 128x128 tile, BK=64, dbuf LDS + T3-min prefetch, XCD-chunk swizzle, y-fast decode.
// EPI 0: LDS-transpose -> bf16 outT[tok][ldo] @ ocol
// EPI 1: same + exact GELU
// EPI 2: swapped-operand acc (rows=tokens) -> float4 resid+store fp32 channel-major
template <int EPI>
__global__ __launch_bounds__(256, 2) void gemm_bt(const __bf16* __restrict__ A, int lda,
                                                  const __bf16* __restrict__ Bt, int ldb,
                                                  int K, int My,
                                                  __bf16* __restrict__ outT, int ldo, int ocol,
                                                  float* __restrict__ outR,
                                                  const float* __restrict__ resid) {
  __shared__ __align__(16) char smem[65536];  // 2 x (A 16K | B 16K); epilogue reuses [0..33792)
  const int tid = threadIdx.x;
  const int lane = tid & 63;
  const int w = tid >> 6;
  const int wr = w >> 1, wc = w & 1;
  const int c = lane & 15, g = lane >> 4;

  // XCD-chunked swizzle (nwg % 8 == 0 for all our launches), then y-fast decode
  const int nwg = gridDim.x;
  int wgid = blockIdx.x;
  if ((nwg & 7) == 0) wgid = ((wgid & 7) * (nwg >> 3)) + (wgid >> 3);
  const int bx = wgid / My;
  const int by = wgid - bx * My;
  const int m0 = by << 7;
  const int n0 = bx << 7;

  auto stage = [&](int buf, int k0) {
    #pragma unroll
    for (int i = 0; i < 4; ++i) {
      int s = (i << 8) + tid;
      int row = s >> 3;
      int kk = ((s ^ row) & 7) << 3;  // pre-swizzled global source -> linear LDS dest
      gload_lds16(A  + (size_t)(m0 + row) * lda + (k0 + kk),
                  smem + (buf << 15) + ((i << 8) + (w << 6)) * 16);
      gload_lds16(Bt + (size_t)(n0 + row) * ldb + (k0 + kk),
                  smem + (buf << 15) + 16384 + ((i << 8) + (w << 6)) * 16);
    }
  };

  f32x4 acc[4][4] = {};
  const int nt = K >> 6;
  stage(0, 0);
  asm volatile("s_waitcnt vmcnt(0)" ::: "memory");
  __syncthreads();
  int cur = 0;
  for (int t = 0; t < nt; ++t) {
    if (t + 1 < nt) stage(cur ^ 1, (t + 1) << 6);
    const char* smA = smem + (cur << 15);
    const char* smB = smA + 16384;
    #pragma unroll
    for (int ks = 0; ks < 2; ++ks) {
      bf16x8 af[4], bfv[4];
      #pragma unroll
      for (int mi = 0; mi < 4; ++mi) {
        int r = (wr << 6) + (mi << 4) + c;
        af[mi] = *(const bf16x8*)(smA + (r << 7) + (((ks << 6) + (g << 4)) ^ ((r & 7) << 4)));
      }
      #pragma unroll
      for (int nj = 0; nj < 4; ++nj) {
        int r = (wc << 6) + (nj << 4) + c;
        bfv[nj] = *(const bf16x8*)(smB + (r << 7) + (((ks << 6) + (g << 4)) ^ ((r & 7) << 4)));
      }
      #pragma unroll
      for (int mi = 0; mi < 4; ++mi)
        #pragma unroll
        for (int nj = 0; nj < 4; ++nj) {
          if constexpr (EPI == 2)  // swapped: C rows = tokens, cols = out-channels
            acc[mi][nj] = __builtin_amdgcn_mfma_f32_16x16x32_bf16(bfv[nj], af[mi], acc[mi][nj], 0, 0, 0);
          else
            acc[mi][nj] = __builtin_amdgcn_mfma_f32_16x16x32_bf16(af[mi], bfv[nj], acc[mi][nj], 0, 0, 0);
        }
    }
    asm volatile("s_waitcnt vmcnt(0)" ::: "memory");
    __syncthreads();
    cur ^= 1;
  }

  if constexpr (EPI <= 1) {
    #pragma unroll
    for (int mi = 0; mi < 4; ++mi)
      #pragma unroll
      for (int nj = 0; nj < 4; ++nj) {
        f32x4 v = acc[mi][nj];
        if constexpr (EPI == 1) {
          #pragma unroll
          for (int r = 0; r < 4; ++r)
            v[r] = 0.5f * v[r] * (1.f + erff(v[r] * 0.70710678f));
        }
        bf16x4 pk = {(__bf16)v[0], (__bf16)v[1], (__bf16)v[2], (__bf16)v[3]};
        int nl = (wc << 6) + (nj << 4) + c;            // token-local
        int ml = (wr << 6) + (mi << 4) + (g << 2);     // m-local
        *(bf16x4*)(smem + nl * 264 + ml * 2) = pk;     // [128][132] bf16
      }
    __syncthreads();
    #pragma unroll
    for (int it = 0; it < 8; ++it) {
      int id = (it << 8) + tid;
      int n = id >> 4, mc = id & 15;
      bf16x8 v = *(const bf16x8*)(smem + n * 264 + (mc << 4));
      *(bf16x8*)(outT + (size_t)(n0 + n) * ldo + (ocol + m0 + (mc << 3))) = v;
    }
  } else {
    // acc fragment: col (c) = out-channel-local, rows (g*4+r) = 4 consecutive tokens
    #pragma unroll
    for (int nj = 0; nj < 4; ++nj) {
      int tokb = n0 + (wc << 6) + (nj << 4) + (g << 2);  // multiple of 4; 4 | 784 -> same image
      unsigned bb = (unsigned)tokb / 784u;
      unsigned pp = (unsigned)tokb - bb * 784u;
      size_t base = (size_t)bb * (384u * 784u) + pp;
      #pragma unroll
      for (int mi = 0; mi < 4; ++mi) {
        int o = m0 + (wr << 6) + (mi << 4) + c;
        size_t a2 = base + (size_t)o * 784u;
        f32x4 rv = *(const f32x4*)(resid + a2);
        f32x4 v = acc[mi][nj] + rv;
        *(f32x4*)(outR + a2) = v;
      }
    }
  }
}

// ---------------- windowed attention: 1 wave per (window, head) ----------------
__global__ __launch_bounds__(256, 2) void attn_kernel(const __bf16* __restrict__ qkv,
                                                      const float* __restrict__ be,
                                                      __bf16* __restrict__ outt) {
  __shared__ __align__(16) char smem_all[4][16384];
  const int tid = threadIdx.x;
  const int lane = tid & 63;
  const int w = tid >> 6;
  char* sm = (char*)smem_all[w];
  const int pair = blockIdx.x * 4 + w;               // 6144 pairs
  const int h = pair % 6;
  const int wg = pair / 6;
  const int b = wg >> 4;
  const int wi = wg & 15;
  const int wh = wi >> 2, wwi = wi & 3;
  const int cc = lane & 15, g = lane >> 4;

  {
    int rsub = lane >> 3;
    int slot = lane & 7;
    int dc = (slot ^ rsub) << 3;
    #pragma unroll
    for (int i = 0; i < 8; ++i) {
      int r = i * 8 + rsub;
      int m = r < 49 ? r : 48;
      int im = div7u(m), jm = m - im * 7;
      int sh = wh * 7 + im + 3; if (sh >= 28) sh -= 28;
      int sw = wwi * 7 + jm + 3; if (sw >= 28) sw -= 28;
      size_t trow = (size_t)(b * 784 + sh * 28 + sw) * 1152;
      gload_lds16(qkv + trow + 384 + h * 64 + dc, sm + i * 1024);         // K
      gload_lds16(qkv + trow +       h * 64 + dc, sm + 8192 + i * 1024);  // Q
    }
  }
  asm volatile("s_waitcnt vmcnt(0)" ::: "memory");
  __syncthreads();

  f32x4 sacc[4][4] = {};
  #pragma unroll
  for (int ks = 0; ks < 2; ++ks) {
    bf16x8 kf[4], qf[4];
    #pragma unroll
    for (int mi = 0; mi < 4; ++mi) {
      int r = (mi << 4) + cc;
      kf[mi] = *(const bf16x8*)(sm + (r << 7) + (((ks << 6) + (g << 4)) ^ ((r & 7) << 4)));
    }
    #pragma unroll
    for (int nj = 0; nj < 4; ++nj) {
      int r = (nj << 4) + cc;
      qf[nj] = *(const bf16x8*)(sm + 8192 + (r << 7) + (((ks << 6) + (g << 4)) ^ ((r & 7) << 4)));
    }
    #pragma unroll
    for (int mi = 0; mi < 4; ++mi)
      #pragma unroll
      for (int nj = 0; nj < 4; ++nj)
        sacc[mi][nj] = __builtin_amdgcn_mfma_f32_16x16x32_bf16(kf[mi], qf[nj], sacc[mi][nj], 0, 0, 0);
  }
  __syncthreads();

  int r9m[4][4];
  #pragma unroll
  for (int mi = 0; mi < 4; ++mi)
    #pragma unroll
    for (int rr = 0; rr < 4; ++rr) {
      int m = (mi << 4) + (g << 2) + rr; if (m > 48) m = 48;
      int im = div7u(m), jm = m - im * 7;
      int sh = wh * 7 + im, sw = wwi * 7 + jm;
      r9m[mi][rr] = ((sh < 21) ? 0 : (sh < 25 ? 1 : 2)) * 3 + ((sw < 21) ? 0 : (sw < 25 ? 1 : 2));
    }

  #pragma unroll
  for (int nj = 0; nj < 4; ++nj) {
    int n = (nj << 4) + cc;
    int ncl = n > 48 ? 48 : n;
    int in_ = div7u(ncl), jn = ncl - in_ * 7;
    int shn = wh * 7 + in_, swn = wwi * 7 + jn;
    int r9n = ((shn < 21) ? 0 : (shn < 25 ? 1 : 2)) * 3 + ((swn < 21) ? 0 : (swn < 25 ? 1 : 2));
    float mx = -1e30f;
    #pragma unroll
    for (int mi = 0; mi < 4; ++mi) {
      f32x4 bia = *(const f32x4*)(be + (((h << 6) + n) << 6) + (mi << 4) + (g << 2));
      #pragma unroll
      for (int rr = 0; rr < 4; ++rr) {
        int m = (mi << 4) + (g << 2) + rr;
        float t = (m < 49)
            ? sacc[mi][nj][rr] * 0.125f + bia[rr] + ((r9m[mi][rr] == r9n) ? 0.f : -100.f)
            : -1e30f;
        sacc[mi][nj][rr] = t;
        mx = fmaxf(mx, t);
      }
    }
    mx = fmaxf(mx, __shfl_xor(mx, 16, 64));
    mx = fmaxf(mx, __shfl_xor(mx, 32, 64));
    float sum = 0.f;
    #pragma unroll
    for (int mi = 0; mi < 4; ++mi)
      #pragma unroll
      for (int rr = 0; rr < 4; ++rr) {
        float e = __expf(sacc[mi][nj][rr] - mx);
        sacc[mi][nj][rr] = e;
        sum += e;
      }
    sum += __shfl_xor(sum, 16, 64);
    sum += __shfl_xor(sum, 32, 64);
    float inv = __builtin_amdgcn_rcpf(sum);
    #pragma unroll
    for (int mi = 0; mi < 4; ++mi) {
      bf16x4 pk = {(__bf16)(sacc[mi][nj][0] * inv), (__bf16)(sacc[mi][nj][1] * inv),
                   (__bf16)(sacc[mi][nj][2] * inv), (__bf16)(sacc[mi][nj][3] * inv)};
      *(bf16x4*)(sm + 8192 + (n << 7) + (((mi << 5) + (g << 3)) ^ ((n & 7) << 4))) = pk;
    }
  }

  {
    int ml = lane & 15, dq = lane >> 4;
    #pragma unroll
    for (int it = 0; it < 4; ++it) {
      int m = (it << 4) + ml;
      int mc_ = m > 48 ? 48 : m;
      int im = div7u(mc_), jm = mc_ - im * 7;
      int sh = wh * 7 + im + 3; if (sh >= 28) sh -= 28;
      int sw = wwi * 7 + jm + 3; if (sw >= 28) sw -= 28;
      const __bf16* gv = qkv + (size_t)(b * 784 + sh * 28 + sw) * 1152 + 768 + h * 64;
      #pragma unroll
      for (int hd = 0; hd < 2; ++hd) {
        int dbase = (hd << 5) + (dq << 3);
        bf16x8 v = *(const bf16x8*)(gv + dbase);
        #pragma unroll
        for (int j = 0; j < 8; ++j) {
          int d = dbase + j;
          *(__bf16*)(sm + (d << 7) + ((((m >> 3) ^ (d & 7)) << 4) + ((m & 7) << 1))) = v[j];
        }
      }
    }
  }
  __syncthreads();

  f32x4 oacc[4][4] = {};
  #pragma unroll
  for (int ks = 0; ks < 2; ++ks) {
    bf16x8 pf[4], vf[4];
    #pragma unroll
    for (int ni = 0; ni < 4; ++ni) {
      int n = (ni << 4) + cc;
      pf[ni] = *(const bf16x8*)(sm + 8192 + (n << 7) + (((ks << 6) + (g << 4)) ^ ((n & 7) << 4)));
    }
    #pragma unroll
    for (int dj = 0; dj < 4; ++dj) {
      int d = (dj << 4) + cc;
      vf[dj] = *(const bf16x8*)(sm + (d << 7) + ((((ks << 2) + g) ^ (d & 7)) << 4));
    }
    #pragma unroll
    for (int ni = 0; ni < 4; ++ni)
      #pragma unroll
      for (int dj = 0; dj < 4; ++dj)
        oacc[ni][dj] = __builtin_amdgcn_mfma_f32_16x16x32_bf16(pf[ni], vf[dj], oacc[ni][dj], 0, 0, 0);
  }

  #pragma unroll
  for (int ni = 0; ni < 4; ++ni)
    #pragma unroll
    for (int rr = 0; rr < 4; ++rr) {
      int n = (ni << 4) + (g << 2) + rr;
      if (n < 49) {
        int im = div7u(n), jn = n - im * 7;
        int sh = wh * 7 + im + 3; if (sh >= 28) sh -= 28;
        int sw = wwi * 7 + jn + 3; if (sw >= 28) sw -= 28;
        __bf16* op = outt + (size_t)(b * 784 + sh * 28 + sw) * 384 + h * 64;
        #pragma unroll
        for (int dj = 0; dj < 4; ++dj)
          op[(dj << 4) + cc] = (__bf16)oacc[ni][dj][rr];
      }
    }
}

// ---------------- host launcher ----------------
extern "C" void kernel_launch(void* const* d_in, const int* in_sizes, int n_in,
                              void* d_out, int out_size, void* d_ws, size_t ws_size,
                              hipStream_t stream) {
  (void)in_sizes; (void)n_in; (void)out_size; (void)ws_size;
  const float* x     = (const float*)d_in[0];
  const float* n1w   = (const float*)d_in[1];
  const float* n1b   = (const float*)d_in[2];
  const float* qkvw  = (const float*)d_in[3];
  const float* tbl   = (const float*)d_in[4];
  const float* projw = (const float*)d_in[5];
  const float* n2w   = (const float*)d_in[6];
  const float* n2b   = (const float*)d_in[7];
  const float* w1    = (const float*)d_in[8];
  const float* w3    = (const float*)d_in[9];
  float* out = (float*)d_out;

  char* ws = (char*)d_ws;
  __bf16* bufA = (__bf16*)ws;                               // 38,535,168 B
  __bf16* bufB = (__bf16*)(ws + 38535168);                  // 115,605,504 B
  float*  be   = (float*)(ws + 154140672);                  // 98,304 B
  __bf16* wq   = (__bf16*)(ws + 154238976);
  __bf16* wp   = wq + 442368;
  __bf16* wm1  = wp + 147456;
  __bf16* wm3  = wm1 + 589824;

  cvt_all_kernel<<<6912, 256, 0, stream>>>(qkvw, projw, w1, w3, wq, wp, wm1, wm3);
  bias_expand_kernel<<<96, 256, 0, stream>>>(tbl, be);

  // LN1 -> xn_t (bufA)
  ln_t_kernel<<<196, 256, 0, stream>>>(x, n1w, n1b, bufA);
  // qkv: [1152x384] @ xn_t -> qkv_t (bufB, token-major)
  gemm_bt<0><<<392 * 9, 256, 0, stream>>>(wq, 384, bufA, 384, 384, 9, bufB, 1152, 0, nullptr, nullptr);
  // attention -> attn_out_t (bufA)
  attn_kernel<<<1536, 256, 0, stream>>>(bufB, be, bufA);
  // proj + residual(x) -> d_out (fp32 channel-major)
  gemm_bt<2><<<392 * 3, 256, 0, stream>>>(wp, 384, bufA, 384, 384, 3, nullptr, 0, 0, out, x);
  // LN2 -> xn2_t (bufA)
  ln_t_kernel<<<196, 256, 0, stream>>>(out, n2w, n2b, bufA);
  // MLP split into two HID halves (h_t reuses bufB, [50176][768])
  for (int pass = 0; pass < 2; ++pass) {
    gemm_bt<1><<<392 * 6, 256, 0, stream>>>(wm1 + (size_t)pass * 768 * 384, 384, bufA, 384, 384, 6,
                                            bufB, 768, 0, nullptr, nullptr);
    gemm_bt<2><<<392 * 3, 256, 0, stream>>>(wm3 + pass * 768, 1536, bufB, 768, 768, 3,
                                            nullptr, 0, 0, out, out);
  }
}

// Round 3
// 470.752 us; speedup vs baseline: 1.1290x; 1.0570x over previous
//
#include <hip/hip_runtime.h>
#include <hip/hip_bf16.h>

// Swin block on MI355X. Round 3: counted-vmcnt pipeline with RAW s_barrier
// (no compiler vmcnt(0) drain), polynomial exact-erf GELU, hoisted staging
// address math. ws layout unchanged.

typedef __bf16 bf16x8 __attribute__((ext_vector_type(8)));
typedef __bf16 bf16x4 __attribute__((ext_vector_type(4)));
typedef float  f32x4  __attribute__((ext_vector_type(4)));

#define GAS __attribute__((address_space(1)))
#define LAS __attribute__((address_space(3)))

__device__ __forceinline__ void gload_lds16(const void* g, void* l) {
  __builtin_amdgcn_global_load_lds((const GAS void*)g, (LAS void*)l, 16, 0, 0);
}

__device__ __forceinline__ int div7u(int m) { return (m * 37) >> 8; }  // valid m<56

// exact GELU via A&S 7.1.26 erf (|err|<=1.5e-7), branch-free:
// gelu(v) = 0.5*v + 0.5*|v|*erf(|v|/sqrt2)
__device__ __forceinline__ float gelu_f(float v) {
  float s = fabsf(v) * 0.70710678118f;
  float t = __builtin_amdgcn_rcpf(__builtin_fmaf(0.3275911f, s, 1.f));
  float p = t * (0.254829592f +
            t * (-0.284496736f +
            t * (1.421413741f +
            t * (-1.453152027f +
            t * 1.061405429f))));
  float erfa = __builtin_fmaf(-p, __expf(-s * s), 1.f);
  return __builtin_fmaf(0.5f * fabsf(v), erfa, 0.5f * v);
}

// ---------------- fp32 -> bf16 weight convert (one launch) ----------------
__global__ __launch_bounds__(256) void cvt_all_kernel(const float* __restrict__ s0,
                                                      const float* __restrict__ s1,
                                                      const float* __restrict__ s2,
                                                      const float* __restrict__ s3,
                                                      __bf16* __restrict__ d0,
                                                      __bf16* __restrict__ d1,
                                                      __bf16* __restrict__ d2,
                                                      __bf16* __restrict__ d3) {
  int i = blockIdx.x * 256 + threadIdx.x;
  if (i < 442368) { d0[i] = (__bf16)s0[i]; return; }
  i -= 442368;
  if (i < 147456) { d1[i] = (__bf16)s1[i]; return; }
  i -= 147456;
  if (i < 589824) { d2[i] = (__bf16)s2[i]; return; }
  i -= 589824;
  d3[i] = (__bf16)s3[i];
}

// ---------------- relative-position bias expand: [6][64][64] ----------------
__global__ __launch_bounds__(256) void bias_expand_kernel(const float* __restrict__ tbl,
                                                          float* __restrict__ be) {
  int idx = blockIdx.x * 256 + threadIdx.x;
  if (idx >= 6 * 64 * 64) return;
  int m = idx & 63, n = (idx >> 6) & 63, h = idx >> 12;
  float v = 0.f;
  if (m < 49 && n < 49) {
    int in_ = div7u(n), jn = n - in_ * 7;
    int im  = div7u(m), jm = m - im * 7;
    int t = (in_ - im + 6) * 13 + (jn - jm + 6);
    v = tbl[t * 6 + h];
  }
  be[idx] = v;
}

// ---------------- LayerNorm(channel) + transpose to token-major bf16 ----------------
__global__ __launch_bounds__(256) void ln_t_kernel(const float* __restrict__ x,
                                                   const float* __restrict__ gw,
                                                   const float* __restrict__ gb,
                                                   __bf16* __restrict__ out) {
  const int tid = threadIdx.x;
  const int tok0 = blockIdx.x << 8;
  const int tok = tok0 + tid;
  const unsigned b = (unsigned)tok / 784u;
  const unsigned p = (unsigned)tok - b * 784u;
  const float* xp = x + (size_t)b * (384u * 784u) + p;
  float s = 0.f, s2 = 0.f;
  for (int c = 0; c < 384; ++c) { float v = xp[c * 784]; s += v; s2 += v * v; }
  float mean = s * (1.f / 384.f);
  float var  = (s2 - s * mean) * (1.f / 383.f);   // unbiased (ddof=1)
  float rstd = rsqrtf(var + 1e-5f);
  __shared__ __align__(16) __bf16 tile[256][40];
  for (int cc = 0; cc < 384; cc += 32) {
    __syncthreads();
    #pragma unroll
    for (int it = 0; it < 32; ++it) {
      float v = xp[(cc + it) * 784];
      tile[tid][it] = (__bf16)((v - mean) * rstd * gw[cc + it] + gb[cc + it]);
    }
    __syncthreads();
    #pragma unroll
    for (int j = 0; j < 4; ++j) {
      int id = (j << 8) + tid;
      int tl = id >> 2, c8 = (id & 3) << 3;
      bf16x8 v = *(const bf16x8*)(&tile[tl][c8]);
      *(bf16x8*)(out + (size_t)(tok0 + tl) * 384 + cc + c8) = v;
    }
  }
}

// ---------------- GEMM: C[m][tok] = sum_k A[m][k] * Bt[tok][k] ----------------
// 128x128 tile, BK=64, dbuf LDS, counted vmcnt(8) pipeline w/ raw s_barrier,
// XCD-chunk swizzle + y-fast decode.
// EPI 0: LDS-transpose -> bf16 outT[tok][ldo] @ ocol
// EPI 1: same + exact GELU (polynomial)
// EPI 2: swapped-operand acc -> float4 resid+store fp32 channel-major
template <int EPI>
__global__ __launch_bounds__(256, 2) void gemm_bt(const __bf16* __restrict__ A, int lda,
                                                  const __bf16* __restrict__ Bt, int ldb,
                                                  int K, int My,
                                                  __bf16* __restrict__ outT, int ldo, int ocol,
                                                  float* __restrict__ outR,
                                                  const float* __restrict__ resid) {
  __shared__ __align__(16) char smem[65536];  // 2 x (A 16K | B 16K); epilogue reuses [0..33792)
  const int tid = threadIdx.x;
  const int lane = tid & 63;
  const int w = tid >> 6;
  const int wr = w >> 1, wc = w & 1;
  const int c = lane & 15, g = lane >> 4;

  // XCD-chunked swizzle (all grids are multiples of 8), then y-fast decode
  const int nwg = gridDim.x;
  int wgid = blockIdx.x;
  wgid = ((wgid & 7) * (nwg >> 3)) + (wgid >> 3);
  const int bx = wgid / My;
  const int by = wgid - bx * My;
  const int m0 = by << 7;
  const int n0 = bx << 7;

  // hoisted staging addresses (pre-swizzled global source -> linear LDS dest)
  const __bf16* ap[4];
  const __bf16* bp[4];
  #pragma unroll
  for (int i = 0; i < 4; ++i) {
    int s = (i << 8) + tid;
    int row = s >> 3;
    int kk = ((s ^ row) & 7) << 3;
    ap[i] = A  + (size_t)(m0 + row) * lda + kk;
    bp[i] = Bt + (size_t)(n0 + row) * ldb + kk;
  }
  auto stage = [&](int buf, int k0) {
    #pragma unroll
    for (int i = 0; i < 4; ++i) {
      gload_lds16(ap[i] + k0, smem + (buf << 15) + (((i << 8) + (w << 6)) << 4));
      gload_lds16(bp[i] + k0, smem + (buf << 15) + 16384 + (((i << 8) + (w << 6)) << 4));
    }
  };

  f32x4 acc[4][4] = {};
  const int nt = K >> 6;
  stage(0, 0);
  int cur = 0;
  for (int t = 0; t < nt; ++t) {
    if (t + 1 < nt) {
      stage(cur ^ 1, (t + 1) << 6);                      // keep 8 loads in flight
      asm volatile("s_waitcnt vmcnt(8)" ::: "memory");   // oldest 8 (tile t) landed
    } else {
      asm volatile("s_waitcnt vmcnt(0)" ::: "memory");
    }
    __builtin_amdgcn_s_barrier();                        // raw: no vmcnt(0) drain
    __builtin_amdgcn_sched_barrier(0);
    const char* smA = smem + (cur << 15);
    const char* smB = smA + 16384;
    #pragma unroll
    for (int ks = 0; ks < 2; ++ks) {
      bf16x8 af[4], bfv[4];
      #pragma unroll
      for (int mi = 0; mi < 4; ++mi) {
        int r = (wr << 6) + (mi << 4) + c;
        af[mi] = *(const bf16x8*)(smA + (r << 7) + (((ks << 6) + (g << 4)) ^ ((r & 7) << 4)));
      }
      #pragma unroll
      for (int nj = 0; nj < 4; ++nj) {
        int r = (wc << 6) + (nj << 4) + c;
        bfv[nj] = *(const bf16x8*)(smB + (r << 7) + (((ks << 6) + (g << 4)) ^ ((r & 7) << 4)));
      }
      #pragma unroll
      for (int mi = 0; mi < 4; ++mi)
        #pragma unroll
        for (int nj = 0; nj < 4; ++nj) {
          if constexpr (EPI == 2)  // swapped: C rows = tokens, cols = out-channels
            acc[mi][nj] = __builtin_amdgcn_mfma_f32_16x16x32_bf16(bfv[nj], af[mi], acc[mi][nj], 0, 0, 0);
          else
            acc[mi][nj] = __builtin_amdgcn_mfma_f32_16x16x32_bf16(af[mi], bfv[nj], acc[mi][nj], 0, 0, 0);
        }
    }
    __builtin_amdgcn_s_barrier();                        // reads of buf[cur] done
    cur ^= 1;
  }

  if constexpr (EPI <= 1) {
    #pragma unroll
    for (int mi = 0; mi < 4; ++mi)
      #pragma unroll
      for (int nj = 0; nj < 4; ++nj) {
        f32x4 v = acc[mi][nj];
        if constexpr (EPI == 1) {
          #pragma unroll
          for (int r = 0; r < 4; ++r) v[r] = gelu_f(v[r]);
        }
        bf16x4 pk = {(__bf16)v[0], (__bf16)v[1], (__bf16)v[2], (__bf16)v[3]};
        int nl = (wc << 6) + (nj << 4) + c;            // token-local
        int ml = (wr << 6) + (mi << 4) + (g << 2);     // m-local
        *(bf16x4*)(smem + nl * 264 + ml * 2) = pk;     // [128][132] bf16
      }
    __syncthreads();
    #pragma unroll
    for (int it = 0; it < 8; ++it) {
      int id = (it << 8) + tid;
      int n = id >> 4, mc = id & 15;
      bf16x8 v = *(const bf16x8*)(smem + n * 264 + (mc << 4));
      *(bf16x8*)(outT + (size_t)(n0 + n) * ldo + (ocol + m0 + (mc << 3))) = v;
    }
  } else {
    // acc fragment: col (c) = out-channel-local, rows (g*4+r) = 4 consecutive tokens
    #pragma unroll
    for (int nj = 0; nj < 4; ++nj) {
      int tokb = n0 + (wc << 6) + (nj << 4) + (g << 2);
      unsigned bb = (unsigned)tokb / 784u;
      unsigned pp = (unsigned)tokb - bb * 784u;
      size_t base = (size_t)bb * (384u * 784u) + pp;
      #pragma unroll
      for (int mi = 0; mi < 4; ++mi) {
        int o = m0 + (wr << 6) + (mi << 4) + c;
        size_t a2 = base + (size_t)o * 784u;
        f32x4 rv = *(const f32x4*)(resid + a2);
        f32x4 v = acc[mi][nj] + rv;
        *(f32x4*)(outR + a2) = v;
      }
    }
  }
}

// ---------------- windowed attention: 1 wave per (window, head) ----------------
__global__ __launch_bounds__(256, 2) void attn_kernel(const __bf16* __restrict__ qkv,
                                                      const float* __restrict__ be,
                                                      __bf16* __restrict__ outt) {
  __shared__ __align__(16) char smem_all[4][16384];
  const int tid = threadIdx.x;
  const int lane = tid & 63;
  const int w = tid >> 6;
  char* sm = (char*)smem_all[w];
  const int pair = blockIdx.x * 4 + w;               // 6144 pairs
  const int h = pair % 6;
  const int wg = pair / 6;
  const int b = wg >> 4;
  const int wi = wg & 15;
  const int wh = wi >> 2, wwi = wi & 3;
  const int cc = lane & 15, g = lane >> 4;

  {
    int rsub = lane >> 3;
    int slot = lane & 7;
    int dc = (slot ^ rsub) << 3;
    #pragma unroll
    for (int i = 0; i < 8; ++i) {
      int r = i * 8 + rsub;
      int m = r < 49 ? r : 48;
      int im = div7u(m), jm = m - im * 7;
      int sh = wh * 7 + im + 3; if (sh >= 28) sh -= 28;
      int sw = wwi * 7 + jm + 3; if (sw >= 28) sw -= 28;
      size_t trow = (size_t)(b * 784 + sh * 28 + sw) * 1152;
      gload_lds16(qkv + trow + 384 + h * 64 + dc, sm + i * 1024);         // K
      gload_lds16(qkv + trow +       h * 64 + dc, sm + 8192 + i * 1024);  // Q
    }
  }
  asm volatile("s_waitcnt vmcnt(0)" ::: "memory");
  __syncthreads();

  f32x4 sacc[4][4] = {};
  #pragma unroll
  for (int ks = 0; ks < 2; ++ks) {
    bf16x8 kf[4], qf[4];
    #pragma unroll
    for (int mi = 0; mi < 4; ++mi) {
      int r = (mi << 4) + cc;
      kf[mi] = *(const bf16x8*)(sm + (r << 7) + (((ks << 6) + (g << 4)) ^ ((r & 7) << 4)));
    }
    #pragma unroll
    for (int nj = 0; nj < 4; ++nj) {
      int r = (nj << 4) + cc;
      qf[nj] = *(const bf16x8*)(sm + 8192 + (r << 7) + (((ks << 6) + (g << 4)) ^ ((r & 7) << 4)));
    }
    #pragma unroll
    for (int mi = 0; mi < 4; ++mi)
      #pragma unroll
      for (int nj = 0; nj < 4; ++nj)
        sacc[mi][nj] = __builtin_amdgcn_mfma_f32_16x16x32_bf16(kf[mi], qf[nj], sacc[mi][nj], 0, 0, 0);
  }
  __syncthreads();

  int r9m[4][4];
  #pragma unroll
  for (int mi = 0; mi < 4; ++mi)
    #pragma unroll
    for (int rr = 0; rr < 4; ++rr) {
      int m = (mi << 4) + (g << 2) + rr; if (m > 48) m = 48;
      int im = div7u(m), jm = m - im * 7;
      int sh = wh * 7 + im, sw = wwi * 7 + jm;
      r9m[mi][rr] = ((sh < 21) ? 0 : (sh < 25 ? 1 : 2)) * 3 + ((sw < 21) ? 0 : (sw < 25 ? 1 : 2));
    }

  #pragma unroll
  for (int nj = 0; nj < 4; ++nj) {
    int n = (nj << 4) + cc;
    int ncl = n > 48 ? 48 : n;
    int in_ = div7u(ncl), jn = ncl - in_ * 7;
    int shn = wh * 7 + in_, swn = wwi * 7 + jn;
    int r9n = ((shn < 21) ? 0 : (shn < 25 ? 1 : 2)) * 3 + ((swn < 21) ? 0 : (swn < 25 ? 1 : 2));
    float mx = -1e30f;
    #pragma unroll
    for (int mi = 0; mi < 4; ++mi) {
      f32x4 bia = *(const f32x4*)(be + (((h << 6) + n) << 6) + (mi << 4) + (g << 2));
      #pragma unroll
      for (int rr = 0; rr < 4; ++rr) {
        int m = (mi << 4) + (g << 2) + rr;
        float t = (m < 49)
            ? sacc[mi][nj][rr] * 0.125f + bia[rr] + ((r9m[mi][rr] == r9n) ? 0.f : -100.f)
            : -1e30f;
        sacc[mi][nj][rr] = t;
        mx = fmaxf(mx, t);
      }
    }
    mx = fmaxf(mx, __shfl_xor(mx, 16, 64));
    mx = fmaxf(mx, __shfl_xor(mx, 32, 64));
    float sum = 0.f;
    #pragma unroll
    for (int mi = 0; mi < 4; ++mi)
      #pragma unroll
      for (int rr = 0; rr < 4; ++rr) {
        float e = __expf(sacc[mi][nj][rr] - mx);
        sacc[mi][nj][rr] = e;
        sum += e;
      }
    sum += __shfl_xor(sum, 16, 64);
    sum += __shfl_xor(sum, 32, 64);
    float inv = __builtin_amdgcn_rcpf(sum);
    #pragma unroll
    for (int mi = 0; mi < 4; ++mi) {
      bf16x4 pk = {(__bf16)(sacc[mi][nj][0] * inv), (__bf16)(sacc[mi][nj][1] * inv),
                   (__bf16)(sacc[mi][nj][2] * inv), (__bf16)(sacc[mi][nj][3] * inv)};
      *(bf16x4*)(sm + 8192 + (n << 7) + (((mi << 5) + (g << 3)) ^ ((n & 7) << 4))) = pk;
    }
  }

  {
    int ml = lane & 15, dq = lane >> 4;
    #pragma unroll
    for (int it = 0; it < 4; ++it) {
      int m = (it << 4) + ml;
      int mc_ = m > 48 ? 48 : m;
      int im = div7u(mc_), jm = mc_ - im * 7;
      int sh = wh * 7 + im + 3; if (sh >= 28) sh -= 28;
      int sw = wwi * 7 + jm + 3; if (sw >= 28) sw -= 28;
      const __bf16* gv = qkv + (size_t)(b * 784 + sh * 28 + sw) * 1152 + 768 + h * 64;
      #pragma unroll
      for (int hd = 0; hd < 2; ++hd) {
        int dbase = (hd << 5) + (dq << 3);
        bf16x8 v = *(const bf16x8*)(gv + dbase);
        #pragma unroll
        for (int j = 0; j < 8; ++j) {
          int d = dbase + j;
          *(__bf16*)(sm + (d << 7) + ((((m >> 3) ^ (d & 7)) << 4) + ((m & 7) << 1))) = v[j];
        }
      }
    }
  }
  __syncthreads();

  f32x4 oacc[4][4] = {};
  #pragma unroll
  for (int ks = 0; ks < 2; ++ks) {
    bf16x8 pf[4], vf[4];
    #pragma unroll
    for (int ni = 0; ni < 4; ++ni) {
      int n = (ni << 4) + cc;
      pf[ni] = *(const bf16x8*)(sm + 8192 + (n << 7) + (((ks << 6) + (g << 4)) ^ ((n & 7) << 4)));
    }
    #pragma unroll
    for (int dj = 0; dj < 4; ++dj) {
      int d = (dj << 4) + cc;
      vf[dj] = *(const bf16x8*)(sm + (d << 7) + ((((ks << 2) + g) ^ (d & 7)) << 4));
    }
    #pragma unroll
    for (int ni = 0; ni < 4; ++ni)
      #pragma unroll
      for (int dj = 0; dj < 4; ++dj)
        oacc[ni][dj] = __builtin_amdgcn_mfma_f32_16x16x32_bf16(pf[ni], vf[dj], oacc[ni][dj], 0, 0, 0);
  }

  #pragma unroll
  for (int ni = 0; ni < 4; ++ni)
    #pragma unroll
    for (int rr = 0; rr < 4; ++rr) {
      int n = (ni << 4) + (g << 2) + rr;
      if (n < 49) {
        int im = div7u(n), jn = n - im * 7;
        int sh = wh * 7 + im + 3; if (sh >= 28) sh -= 28;
        int sw = wwi * 7 + jn + 3; if (sw >= 28) sw -= 28;
        __bf16* op = outt + (size_t)(b * 784 + sh * 28 + sw) * 384 + h * 64;
        #pragma unroll
        for (int dj = 0; dj < 4; ++dj)
          op[(dj << 4) + cc] = (__bf16)oacc[ni][dj][rr];
      }
    }
}

// ---------------- host launcher ----------------
extern "C" void kernel_launch(void* const* d_in, const int* in_sizes, int n_in,
                              void* d_out, int out_size, void* d_ws, size_t ws_size,
                              hipStream_t stream) {
  (void)in_sizes; (void)n_in; (void)out_size; (void)ws_size;
  const float* x     = (const float*)d_in[0];
  const float* n1w   = (const float*)d_in[1];
  const float* n1b   = (const float*)d_in[2];
  const float* qkvw  = (const float*)d_in[3];
  const float* tbl   = (const float*)d_in[4];
  const float* projw = (const float*)d_in[5];
  const float* n2w   = (const float*)d_in[6];
  const float* n2b   = (const float*)d_in[7];
  const float* w1    = (const float*)d_in[8];
  const float* w3    = (const float*)d_in[9];
  float* out = (float*)d_out;

  char* ws = (char*)d_ws;
  __bf16* bufA = (__bf16*)ws;                               // 38,535,168 B
  __bf16* bufB = (__bf16*)(ws + 38535168);                  // 115,605,504 B
  float*  be   = (float*)(ws + 154140672);                  // 98,304 B
  __bf16* wq   = (__bf16*)(ws + 154238976);
  __bf16* wp   = wq + 442368;
  __bf16* wm1  = wp + 147456;
  __bf16* wm3  = wm1 + 589824;

  cvt_all_kernel<<<6912, 256, 0, stream>>>(qkvw, projw, w1, w3, wq, wp, wm1, wm3);
  bias_expand_kernel<<<96, 256, 0, stream>>>(tbl, be);

  // LN1 -> xn_t (bufA)
  ln_t_kernel<<<196, 256, 0, stream>>>(x, n1w, n1b, bufA);
  // qkv: [1152x384] @ xn_t -> qkv_t (bufB, token-major)
  gemm_bt<0><<<392 * 9, 256, 0, stream>>>(wq, 384, bufA, 384, 384, 9, bufB, 1152, 0, nullptr, nullptr);
  // attention -> attn_out_t (bufA)
  attn_kernel<<<1536, 256, 0, stream>>>(bufB, be, bufA);
  // proj + residual(x) -> d_out (fp32 channel-major)
  gemm_bt<2><<<392 * 3, 256, 0, stream>>>(wp, 384, bufA, 384, 384, 3, nullptr, 0, 0, out, x);
  // LN2 -> xn2_t (bufA)
  ln_t_kernel<<<196, 256, 0, stream>>>(out, n2w, n2b, bufA);
  // MLP split into two HID halves (h_t reuses bufB, [50176][768])
  for (int pass = 0; pass < 2; ++pass) {
    gemm_bt<1><<<392 * 6, 256, 0, stream>>>(wm1 + (size_t)pass * 768 * 384, 384, bufA, 384, 384, 6,
                                            bufB, 768, 0, nullptr, nullptr);
    gemm_bt<2><<<392 * 3, 256, 0, stream>>>(wm3 + pass * 768, 1536, bufB, 768, 768, 3,
                                            nullptr, 0, 0, out, out);
  }
}

// Round 5
// 434.399 us; speedup vs baseline: 1.2235x; 1.0837x over previous
//
#include <hip/hip_runtime.h>
#include <hip/hip_bf16.h>

// Swin block on MI355X. Round 5: round 4 + BIJECTIVE XCD-chunk swizzle (m204)
// — round 4's non-bijective swizzle dropped tiles when nwg%8!=0 (mlp2: 588).

typedef __bf16 bf16x8 __attribute__((ext_vector_type(8)));
typedef __bf16 bf16x4 __attribute__((ext_vector_type(4)));
typedef float  f32x4  __attribute__((ext_vector_type(4)));

#define GAS __attribute__((address_space(1)))
#define LAS __attribute__((address_space(3)))

__device__ __forceinline__ void gload_lds16(const void* g, void* l) {
  __builtin_amdgcn_global_load_lds((const GAS void*)g, (LAS void*)l, 16, 0, 0);
}

__device__ __forceinline__ int div7u(int m) { return (m * 37) >> 8; }  // valid m<56

// exact GELU via A&S 7.1.26 erf (|err|<=1.5e-7), branch-free
__device__ __forceinline__ float gelu_f(float v) {
  float s = fabsf(v) * 0.70710678118f;
  float t = __builtin_amdgcn_rcpf(__builtin_fmaf(0.3275911f, s, 1.f));
  float p = t * (0.254829592f +
            t * (-0.284496736f +
            t * (1.421413741f +
            t * (-1.453152027f +
            t * 1.061405429f))));
  float erfa = __builtin_fmaf(-p, __expf(-s * s), 1.f);
  return __builtin_fmaf(0.5f * fabsf(v), erfa, 0.5f * v);
}

// ---------------- fp32 -> bf16 weight convert (one launch) ----------------
__global__ __launch_bounds__(256) void cvt_all_kernel(const float* __restrict__ s0,
                                                      const float* __restrict__ s1,
                                                      const float* __restrict__ s2,
                                                      const float* __restrict__ s3,
                                                      __bf16* __restrict__ d0,
                                                      __bf16* __restrict__ d1,
                                                      __bf16* __restrict__ d2,
                                                      __bf16* __restrict__ d3) {
  int i = blockIdx.x * 256 + threadIdx.x;
  if (i < 442368) { d0[i] = (__bf16)s0[i]; return; }
  i -= 442368;
  if (i < 147456) { d1[i] = (__bf16)s1[i]; return; }
  i -= 147456;
  if (i < 589824) { d2[i] = (__bf16)s2[i]; return; }
  i -= 589824;
  d3[i] = (__bf16)s3[i];
}

// ---------------- relative-position bias expand: [6][64][64] ----------------
__global__ __launch_bounds__(256) void bias_expand_kernel(const float* __restrict__ tbl,
                                                          float* __restrict__ be) {
  int idx = blockIdx.x * 256 + threadIdx.x;
  if (idx >= 6 * 64 * 64) return;
  int m = idx & 63, n = (idx >> 6) & 63, h = idx >> 12;
  float v = 0.f;
  if (m < 49 && n < 49) {
    int in_ = div7u(n), jn = n - in_ * 7;
    int im  = div7u(m), jm = m - im * 7;
    int t = (in_ - im + 6) * 13 + (jn - jm + 6);
    v = tbl[t * 6 + h];
  }
  be[idx] = v;
}

// ---------------- LayerNorm(channel) + transpose to token-major bf16 ----------------
// 64 tokens/block, 4 waves = 4 channel groups of 96. x: [64][384][784] f32.
__global__ __launch_bounds__(256) void ln_t_kernel(const float* __restrict__ x,
                                                   const float* __restrict__ gw,
                                                   const float* __restrict__ gb,
                                                   __bf16* __restrict__ out) {
  __shared__ float ps[4][64], ps2[4][64];
  __shared__ __align__(16) __bf16 tile[64][392];   // row stride 784 B (49x16B)
  const int tid = threadIdx.x;
  const int w = tid >> 6, t = tid & 63;
  const int tok0 = blockIdx.x << 6;
  const int tok = tok0 + t;
  const unsigned b = (unsigned)tok / 784u;
  const unsigned p = (unsigned)tok - b * 784u;
  const float* xp = x + (size_t)b * 301056u + p;   // 384*784
  const int c0 = w * 96;
  float s = 0.f, s2 = 0.f;
  #pragma unroll 4
  for (int c = c0; c < c0 + 96; ++c) { float v = xp[c * 784]; s += v; s2 += v * v; }
  ps[w][t] = s; ps2[w][t] = s2;
  __syncthreads();
  float S  = ps[0][t] + ps[1][t] + ps[2][t] + ps[3][t];
  float S2 = ps2[0][t] + ps2[1][t] + ps2[2][t] + ps2[3][t];
  float mean = S * (1.f / 384.f);
  float var  = (S2 - S * mean) * (1.f / 383.f);    // unbiased (ddof=1)
  float rstd = rsqrtf(var + 1e-5f);
  #pragma unroll
  for (int cc = c0; cc < c0 + 96; cc += 8) {
    bf16x8 pk;
    #pragma unroll
    for (int j = 0; j < 8; ++j) {
      float v = xp[(cc + j) * 784];
      pk[j] = (__bf16)((v - mean) * rstd * gw[cc + j] + gb[cc + j]);
    }
    *(bf16x8*)(&tile[t][cc]) = pk;
  }
  __syncthreads();
  #pragma unroll
  for (int it = 0; it < 12; ++it) {
    int idx = (it << 8) + tid;
    int row = idx / 48, col = idx - row * 48;      // 48 x 16B chunks per row
    bf16x8 v = *(const bf16x8*)(&tile[row][col << 3]);
    *(bf16x8*)(out + (size_t)(tok0 + row) * 384 + (col << 3)) = v;
  }
}

// ---------------- GEMM: C[m][tok] = sum_k A[m][k] * Bt[tok][k] ----------------
// 128x128 tile, BK=64, dbuf LDS, counted vmcnt(8) pipeline w/ raw s_barrier,
// bijective XCD-chunk swizzle (m204) + y-fast decode.
// EPI 0: LDS-transpose -> bf16 outT[tok][ldo] @ ocol
// EPI 1: same + exact GELU (polynomial)
// EPI 2: swapped-operand acc -> float4 resid+store fp32 channel-major (global
//        token = tok_off + local)
template <int EPI>
__global__ __launch_bounds__(256, 2) void gemm_bt(const __bf16* __restrict__ A, int lda,
                                                  const __bf16* __restrict__ Bt, int ldb,
                                                  int K, int My,
                                                  __bf16* __restrict__ outT, int ldo, int ocol,
                                                  float* __restrict__ outR,
                                                  const float* __restrict__ resid,
                                                  int tok_off) {
  __shared__ __align__(16) char smem[65536];
  const int tid = threadIdx.x;
  const int lane = tid & 63;
  const int w = tid >> 6;
  const int wr = w >> 1, wc = w & 1;
  const int c = lane & 15, g = lane >> 4;

  // bijective XCD-chunked swizzle (valid for any nwg), then y-fast decode
  const int nwg = gridDim.x;
  {
  }
  const int orig = blockIdx.x;
  const int q = nwg >> 3, r = nwg & 7;
  const int xcd = orig & 7, ii = orig >> 3;
  const int base = xcd < r ? xcd * (q + 1) : r * (q + 1) + (xcd - r) * q;
  const int wgid = base + ii;
  const int bx = wgid / My;
  const int by = wgid - bx * My;
  const int m0 = by << 7;
  const int n0 = bx << 7;

  const __bf16* ap[4];
  const __bf16* bp[4];
  #pragma unroll
  for (int i = 0; i < 4; ++i) {
    int s = (i << 8) + tid;
    int row = s >> 3;
    int kk = ((s ^ row) & 7) << 3;
    ap[i] = A  + (size_t)(m0 + row) * lda + kk;
    bp[i] = Bt + (size_t)(n0 + row) * ldb + kk;
  }
  auto stage = [&](int buf, int k0) {
    #pragma unroll
    for (int i = 0; i < 4; ++i) {
      gload_lds16(ap[i] + k0, smem + (buf << 15) + (((i << 8) + (w << 6)) << 4));
      gload_lds16(bp[i] + k0, smem + (buf << 15) + 16384 + (((i << 8) + (w << 6)) << 4));
    }
  };

  f32x4 acc[4][4] = {};
  const int nt = K >> 6;
  stage(0, 0);
  int cur = 0;
  for (int t = 0; t < nt; ++t) {
    if (t + 1 < nt) {
      stage(cur ^ 1, (t + 1) << 6);                      // keep 8 loads in flight
      asm volatile("s_waitcnt vmcnt(8)" ::: "memory");   // oldest 8 (tile t) landed
    } else {
      asm volatile("s_waitcnt vmcnt(0)" ::: "memory");
    }
    __builtin_amdgcn_s_barrier();
    __builtin_amdgcn_sched_barrier(0);
    const char* smA = smem + (cur << 15);
    const char* smB = smA + 16384;
    #pragma unroll
    for (int ks = 0; ks < 2; ++ks) {
      bf16x8 af[4], bfv[4];
      #pragma unroll
      for (int mi = 0; mi < 4; ++mi) {
        int r2 = (wr << 6) + (mi << 4) + c;
        af[mi] = *(const bf16x8*)(smA + (r2 << 7) + (((ks << 6) + (g << 4)) ^ ((r2 & 7) << 4)));
      }
      #pragma unroll
      for (int nj = 0; nj < 4; ++nj) {
        int r2 = (wc << 6) + (nj << 4) + c;
        bfv[nj] = *(const bf16x8*)(smB + (r2 << 7) + (((ks << 6) + (g << 4)) ^ ((r2 & 7) << 4)));
      }
      #pragma unroll
      for (int mi = 0; mi < 4; ++mi)
        #pragma unroll
        for (int nj = 0; nj < 4; ++nj) {
          if constexpr (EPI == 2)  // swapped: C rows = tokens
            acc[mi][nj] = __builtin_amdgcn_mfma_f32_16x16x32_bf16(bfv[nj], af[mi], acc[mi][nj], 0, 0, 0);
          else
            acc[mi][nj] = __builtin_amdgcn_mfma_f32_16x16x32_bf16(af[mi], bfv[nj], acc[mi][nj], 0, 0, 0);
        }
    }
    __builtin_amdgcn_s_barrier();
    cur ^= 1;
  }

  if constexpr (EPI <= 1) {
    #pragma unroll
    for (int mi = 0; mi < 4; ++mi)
      #pragma unroll
      for (int nj = 0; nj < 4; ++nj) {
        f32x4 v = acc[mi][nj];
        if constexpr (EPI == 1) {
          #pragma unroll
          for (int r2 = 0; r2 < 4; ++r2) v[r2] = gelu_f(v[r2]);
        }
        bf16x4 pk = {(__bf16)v[0], (__bf16)v[1], (__bf16)v[2], (__bf16)v[3]};
        int nl = (wc << 6) + (nj << 4) + c;
        int ml = (wr << 6) + (mi << 4) + (g << 2);
        *(bf16x4*)(smem + nl * 264 + ml * 2) = pk;
      }
    __syncthreads();
    #pragma unroll
    for (int it = 0; it < 8; ++it) {
      int id = (it << 8) + tid;
      int n = id >> 4, mc = id & 15;
      bf16x8 v = *(const bf16x8*)(smem + n * 264 + (mc << 4));
      *(bf16x8*)(outT + (size_t)(n0 + n) * ldo + (ocol + m0 + (mc << 3))) = v;
    }
  } else {
    #pragma unroll
    for (int nj = 0; nj < 4; ++nj) {
      int tokb = tok_off + n0 + (wc << 6) + (nj << 4) + (g << 2);
      unsigned bb = (unsigned)tokb / 784u;
      unsigned pp = (unsigned)tokb - bb * 784u;
      size_t base2 = (size_t)bb * (384u * 784u) + pp;
      #pragma unroll
      for (int mi = 0; mi < 4; ++mi) {
        int o = m0 + (wr << 6) + (mi << 4) + c;
        size_t a2 = base2 + (size_t)o * 784u;
        f32x4 rv = *(const f32x4*)(resid + a2);
        f32x4 v = acc[mi][nj] + rv;
        *(f32x4*)(outR + a2) = v;
      }
    }
  }
}

// ---------------- windowed attention: 1 wave per (window, head) ----------------
__global__ __launch_bounds__(256, 2) void attn_kernel(const __bf16* __restrict__ qkv,
                                                      const float* __restrict__ be,
                                                      __bf16* __restrict__ outt) {
  __shared__ __align__(16) char smem_all[4][16384];
  const int tid = threadIdx.x;
  const int lane = tid & 63;
  const int w = tid >> 6;
  char* sm = (char*)smem_all[w];
  const int pair = blockIdx.x * 4 + w;               // 6144 pairs
  const int h = pair % 6;
  const int wg = pair / 6;
  const int b = wg >> 4;
  const int wi = wg & 15;
  const int wh = wi >> 2, wwi = wi & 3;
  const int cc = lane & 15, g = lane >> 4;

  {
    int rsub = lane >> 3;
    int slot = lane & 7;
    int dc = (slot ^ rsub) << 3;
    #pragma unroll
    for (int i = 0; i < 8; ++i) {
      int r = i * 8 + rsub;
      int m = r < 49 ? r : 48;
      int im = div7u(m), jm = m - im * 7;
      int sh = wh * 7 + im + 3; if (sh >= 28) sh -= 28;
      int sw = wwi * 7 + jm + 3; if (sw >= 28) sw -= 28;
      size_t trow = (size_t)(b * 784 + sh * 28 + sw) * 1152;
      gload_lds16(qkv + trow + 384 + h * 64 + dc, sm + i * 1024);         // K
      gload_lds16(qkv + trow +       h * 64 + dc, sm + 8192 + i * 1024);  // Q
    }
  }
  asm volatile("s_waitcnt vmcnt(0)" ::: "memory");
  __syncthreads();

  f32x4 sacc[4][4] = {};
  #pragma unroll
  for (int ks = 0; ks < 2; ++ks) {
    bf16x8 kf[4], qf[4];
    #pragma unroll
    for (int mi = 0; mi < 4; ++mi) {
      int r = (mi << 4) + cc;
      kf[mi] = *(const bf16x8*)(sm + (r << 7) + (((ks << 6) + (g << 4)) ^ ((r & 7) << 4)));
    }
    #pragma unroll
    for (int nj = 0; nj < 4; ++nj) {
      int r = (nj << 4) + cc;
      qf[nj] = *(const bf16x8*)(sm + 8192 + (r << 7) + (((ks << 6) + (g << 4)) ^ ((r & 7) << 4)));
    }
    #pragma unroll
    for (int mi = 0; mi < 4; ++mi)
      #pragma unroll
      for (int nj = 0; nj < 4; ++nj)
        sacc[mi][nj] = __builtin_amdgcn_mfma_f32_16x16x32_bf16(kf[mi], qf[nj], sacc[mi][nj], 0, 0, 0);
  }
  __syncthreads();

  int r9m[4][4];
  #pragma unroll
  for (int mi = 0; mi < 4; ++mi)
    #pragma unroll
    for (int rr = 0; rr < 4; ++rr) {
      int m = (mi << 4) + (g << 2) + rr; if (m > 48) m = 48;
      int im = div7u(m), jm = m - im * 7;
      int sh = wh * 7 + im, sw = wwi * 7 + jm;
      r9m[mi][rr] = ((sh < 21) ? 0 : (sh < 25 ? 1 : 2)) * 3 + ((sw < 21) ? 0 : (sw < 25 ? 1 : 2));
    }

  #pragma unroll
  for (int nj = 0; nj < 4; ++nj) {
    int n = (nj << 4) + cc;
    int ncl = n > 48 ? 48 : n;
    int in_ = div7u(ncl), jn = ncl - in_ * 7;
    int shn = wh * 7 + in_, swn = wwi * 7 + jn;
    int r9n = ((shn < 21) ? 0 : (shn < 25 ? 1 : 2)) * 3 + ((swn < 21) ? 0 : (swn < 25 ? 1 : 2));
    float mx = -1e30f;
    #pragma unroll
    for (int mi = 0; mi < 4; ++mi) {
      f32x4 bia = *(const f32x4*)(be + (((h << 6) + n) << 6) + (mi << 4) + (g << 2));
      #pragma unroll
      for (int rr = 0; rr < 4; ++rr) {
        int m = (mi << 4) + (g << 2) + rr;
        float t = (m < 49)
            ? sacc[mi][nj][rr] * 0.125f + bia[rr] + ((r9m[mi][rr] == r9n) ? 0.f : -100.f)
            : -1e30f;
        sacc[mi][nj][rr] = t;
        mx = fmaxf(mx, t);
      }
    }
    mx = fmaxf(mx, __shfl_xor(mx, 16, 64));
    mx = fmaxf(mx, __shfl_xor(mx, 32, 64));
    float sum = 0.f;
    #pragma unroll
    for (int mi = 0; mi < 4; ++mi)
      #pragma unroll
      for (int rr = 0; rr < 4; ++rr) {
        float e = __expf(sacc[mi][nj][rr] - mx);
        sacc[mi][nj][rr] = e;
        sum += e;
      }
    sum += __shfl_xor(sum, 16, 64);
    sum += __shfl_xor(sum, 32, 64);
    float inv = __builtin_amdgcn_rcpf(sum);
    #pragma unroll
    for (int mi = 0; mi < 4; ++mi) {
      bf16x4 pk = {(__bf16)(sacc[mi][nj][0] * inv), (__bf16)(sacc[mi][nj][1] * inv),
                   (__bf16)(sacc[mi][nj][2] * inv), (__bf16)(sacc[mi][nj][3] * inv)};
      *(bf16x4*)(sm + 8192 + (n << 7) + (((mi << 5) + (g << 3)) ^ ((n & 7) << 4))) = pk;
    }
  }

  {
    int ml = lane & 15, dq = lane >> 4;
    #pragma unroll
    for (int it = 0; it < 4; ++it) {
      int m = (it << 4) + ml;
      int mc_ = m > 48 ? 48 : m;
      int im = div7u(mc_), jm = mc_ - im * 7;
      int sh = wh * 7 + im + 3; if (sh >= 28) sh -= 28;
      int sw = wwi * 7 + jm + 3; if (sw >= 28) sw -= 28;
      const __bf16* gv = qkv + (size_t)(b * 784 + sh * 28 + sw) * 1152 + 768 + h * 64;
      #pragma unroll
      for (int hd = 0; hd < 2; ++hd) {
        int dbase = (hd << 5) + (dq << 3);
        bf16x8 v = *(const bf16x8*)(gv + dbase);
        #pragma unroll
        for (int j = 0; j < 8; ++j) {
          int d = dbase + j;
          *(__bf16*)(sm + (d << 7) + ((((m >> 3) ^ (d & 7)) << 4) + ((m & 7) << 1))) = v[j];
        }
      }
    }
  }
  __syncthreads();

  f32x4 oacc[4][4] = {};
  #pragma unroll
  for (int ks = 0; ks < 2; ++ks) {
    bf16x8 pf[4], vf[4];
    #pragma unroll
    for (int ni = 0; ni < 4; ++ni) {
      int n = (ni << 4) + cc;
      pf[ni] = *(const bf16x8*)(sm + 8192 + (n << 7) + (((ks << 6) + (g << 4)) ^ ((n & 7) << 4)));
    }
    #pragma unroll
    for (int dj = 0; dj < 4; ++dj) {
      int d = (dj << 4) + cc;
      vf[dj] = *(const bf16x8*)(sm + (d << 7) + ((((ks << 2) + g) ^ (d & 7)) << 4));
    }
    #pragma unroll
    for (int ni = 0; ni < 4; ++ni)
      #pragma unroll
      for (int dj = 0; dj < 4; ++dj)
        oacc[ni][dj] = __builtin_amdgcn_mfma_f32_16x16x32_bf16(pf[ni], vf[dj], oacc[ni][dj], 0, 0, 0);
  }

  #pragma unroll
  for (int ni = 0; ni < 4; ++ni)
    #pragma unroll
    for (int rr = 0; rr < 4; ++rr) {
      int n = (ni << 4) + (g << 2) + rr;
      if (n < 49) {
        int im = div7u(n), jn = n - im * 7;
        int sh = wh * 7 + im + 3; if (sh >= 28) sh -= 28;
        int sw = wwi * 7 + jn + 3; if (sw >= 28) sw -= 28;
        __bf16* op = outt + (size_t)(b * 784 + sh * 28 + sw) * 384 + h * 64;
        #pragma unroll
        for (int dj = 0; dj < 4; ++dj)
          op[(dj << 4) + cc] = (__bf16)oacc[ni][dj][rr];
      }
    }
}

// ---------------- host launcher ----------------
extern "C" void kernel_launch(void* const* d_in, const int* in_sizes, int n_in,
                              void* d_out, int out_size, void* d_ws, size_t ws_size,
                              hipStream_t stream) {
  (void)in_sizes; (void)n_in; (void)out_size; (void)ws_size;
  const float* x     = (const float*)d_in[0];
  const float* n1w   = (const float*)d_in[1];
  const float* n1b   = (const float*)d_in[2];
  const float* qkvw  = (const float*)d_in[3];
  const float* tbl   = (const float*)d_in[4];
  const float* projw = (const float*)d_in[5];
  const float* n2w   = (const float*)d_in[6];
  const float* n2b   = (const float*)d_in[7];
  const float* w1    = (const float*)d_in[8];
  const float* w3    = (const float*)d_in[9];
  float* out = (float*)d_out;

  char* ws = (char*)d_ws;
  __bf16* bufA = (__bf16*)ws;                               // 38,535,168 B
  __bf16* bufB = (__bf16*)(ws + 38535168);                  // 115,605,504 B
  float*  be   = (float*)(ws + 154140672);                  // 98,304 B
  __bf16* wq   = (__bf16*)(ws + 154238976);
  __bf16* wp   = wq + 442368;
  __bf16* wm1  = wp + 147456;
  __bf16* wm3  = wm1 + 589824;

  cvt_all_kernel<<<6912, 256, 0, stream>>>(qkvw, projw, w1, w3, wq, wp, wm1, wm3);
  bias_expand_kernel<<<96, 256, 0, stream>>>(tbl, be);

  // LN1 -> xn_t (bufA)
  ln_t_kernel<<<784, 256, 0, stream>>>(x, n1w, n1b, bufA);
  // qkv: [1152x384] @ xn_t -> qkv_t (bufB, token-major)
  gemm_bt<0><<<392 * 9, 256, 0, stream>>>(wq, 384, bufA, 384, 384, 9, bufB, 1152, 0,
                                          nullptr, nullptr, 0);
  // attention -> attn_out_t (bufA)
  attn_kernel<<<1536, 256, 0, stream>>>(bufB, be, bufA);
  // proj + residual(x) -> d_out (fp32 channel-major)
  gemm_bt<2><<<392 * 3, 256, 0, stream>>>(wp, 384, bufA, 384, 384, 3, nullptr, 0, 0,
                                          out, x, 0);
  // LN2 -> xn2_t (bufA)
  ln_t_kernel<<<784, 256, 0, stream>>>(out, n2w, n2b, bufA);
  // MLP, token-split halves: full HID=1536 per half; h-half [25088][1536] in bufB
  for (int hh = 0; hh < 2; ++hh) {
    const int toff = hh * 25088;
    gemm_bt<1><<<196 * 12, 256, 0, stream>>>(wm1, 384, bufA + (size_t)toff * 384, 384, 384, 12,
                                             bufB, 1536, 0, nullptr, nullptr, 0);
    gemm_bt<2><<<196 * 3, 256, 0, stream>>>(wm3, 1536, bufB, 1536, 1536, 3,
                                            nullptr, 0, 0, out, out, toff);
  }
}

// Round 6
// 399.113 us; speedup vs baseline: 1.3317x; 1.0884x over previous
//
#include <hip/hip_runtime.h>
#include <hip/hip_bf16.h>

// Swin block on MI355X. Round 6: LN rewrite — float4 token-group loads, values
// held in registers (single global read), LDS-transpose bf16 write-out.
// GEMM/attention pipeline unchanged from round 5.

typedef __bf16 bf16x8 __attribute__((ext_vector_type(8)));
typedef __bf16 bf16x4 __attribute__((ext_vector_type(4)));
typedef float  f32x4  __attribute__((ext_vector_type(4)));

#define GAS __attribute__((address_space(1)))
#define LAS __attribute__((address_space(3)))

__device__ __forceinline__ void gload_lds16(const void* g, void* l) {
  __builtin_amdgcn_global_load_lds((const GAS void*)g, (LAS void*)l, 16, 0, 0);
}

__device__ __forceinline__ int div7u(int m) { return (m * 37) >> 8; }  // valid m<56

// exact GELU via A&S 7.1.26 erf (|err|<=1.5e-7), branch-free
__device__ __forceinline__ float gelu_f(float v) {
  float s = fabsf(v) * 0.70710678118f;
  float t = __builtin_amdgcn_rcpf(__builtin_fmaf(0.3275911f, s, 1.f));
  float p = t * (0.254829592f +
            t * (-0.284496736f +
            t * (1.421413741f +
            t * (-1.453152027f +
            t * 1.061405429f))));
  float erfa = __builtin_fmaf(-p, __expf(-s * s), 1.f);
  return __builtin_fmaf(0.5f * fabsf(v), erfa, 0.5f * v);
}

// ---------------- fp32 -> bf16 weight convert (one launch) ----------------
__global__ __launch_bounds__(256) void cvt_all_kernel(const float* __restrict__ s0,
                                                      const float* __restrict__ s1,
                                                      const float* __restrict__ s2,
                                                      const float* __restrict__ s3,
                                                      __bf16* __restrict__ d0,
                                                      __bf16* __restrict__ d1,
                                                      __bf16* __restrict__ d2,
                                                      __bf16* __restrict__ d3) {
  int i = blockIdx.x * 256 + threadIdx.x;
  if (i < 442368) { d0[i] = (__bf16)s0[i]; return; }
  i -= 442368;
  if (i < 147456) { d1[i] = (__bf16)s1[i]; return; }
  i -= 147456;
  if (i < 589824) { d2[i] = (__bf16)s2[i]; return; }
  i -= 589824;
  d3[i] = (__bf16)s3[i];
}

// ---------------- relative-position bias expand: [6][64][64] ----------------
__global__ __launch_bounds__(256) void bias_expand_kernel(const float* __restrict__ tbl,
                                                          float* __restrict__ be) {
  int idx = blockIdx.x * 256 + threadIdx.x;
  if (idx >= 6 * 64 * 64) return;
  int m = idx & 63, n = (idx >> 6) & 63, h = idx >> 12;
  float v = 0.f;
  if (m < 49 && n < 49) {
    int in_ = div7u(n), jn = n - in_ * 7;
    int im  = div7u(m), jm = m - im * 7;
    int t = (in_ - im + 6) * 13 + (jn - jm + 6);
    v = tbl[t * 6 + h];
  }
  be[idx] = v;
}

// ---------------- LayerNorm(channel) + transpose to token-major bf16 ----------------
// 64 tokens/block as 16 float4 token-groups x 16 channel-subs (12 ch each).
// Single global read: values held in registers. x: [64][384][784] f32.
__global__ __launch_bounds__(256) void ln_t_kernel(const float* __restrict__ x,
                                                   const float* __restrict__ gw,
                                                   const float* __restrict__ gb,
                                                   __bf16* __restrict__ out) {
  __shared__ f32x4 ps[16][16], ps2[16][16];        // [sub][gq]
  __shared__ __align__(16) __bf16 tile[64][198];   // 198: 4-row stride = 12 dw mod 32
  const int tid = threadIdx.x;
  const int lane = tid & 63, w = tid >> 6;
  const int gq = lane & 15;                        // token group within block
  const int sub = (w << 2) + (lane >> 4);          // 0..15 channel sub
  const int tok0 = blockIdx.x << 6;
  const int tokg4 = tok0 + (gq << 2);              // first of 4 tokens (4|784: same image)
  const unsigned b = (unsigned)tokg4 / 784u;
  const unsigned p = (unsigned)tokg4 - b * 784u;
  const float* xp = x + (size_t)b * 301056u + p;

  f32x4 vals[24];
  f32x4 s4 = {0.f, 0.f, 0.f, 0.f}, s24 = {0.f, 0.f, 0.f, 0.f};
  #pragma unroll
  for (int half = 0; half < 2; ++half)
    #pragma unroll
    for (int k = 0; k < 12; ++k) {
      int c = half * 192 + sub * 12 + k;
      f32x4 v = *(const f32x4*)(xp + (size_t)c * 784u);
      vals[half * 12 + k] = v;
      s4 += v;
      s24 += v * v;
    }
  ps[sub][gq] = s4;
  ps2[sub][gq] = s24;
  __syncthreads();
  f32x4 S = {0.f, 0.f, 0.f, 0.f}, S2 = {0.f, 0.f, 0.f, 0.f};
  #pragma unroll
  for (int i = 0; i < 16; ++i) { S += ps[i][gq]; S2 += ps2[i][gq]; }
  f32x4 mean = S * (1.f / 384.f);
  f32x4 var = (S2 - S * mean) * (1.f / 383.f);     // unbiased (ddof=1)
  f32x4 rstd;
  #pragma unroll
  for (int j = 0; j < 4; ++j) rstd[j] = rsqrtf(var[j] + 1e-5f);

  #pragma unroll
  for (int half = 0; half < 2; ++half) {
    if (half) __syncthreads();                     // prev drain done before overwrite
    #pragma unroll
    for (int k = 0; k < 12; ++k) {
      int c = half * 192 + sub * 12 + k;
      float wgt = gw[c], bia = gb[c];
      f32x4 v = (vals[half * 12 + k] - mean) * rstd * wgt + bia;
      #pragma unroll
      for (int j = 0; j < 4; ++j)
        tile[(gq << 2) + j][sub * 12 + k] = (__bf16)v[j];
    }
    __syncthreads();
    #pragma unroll
    for (int it = 0; it < 6; ++it) {
      int idx = (it << 8) + tid;
      int row = idx / 24, colc = idx - row * 24;   // 24 x 16B chunks per row
      bf16x8 vv = *(const bf16x8*)(&tile[row][colc << 3]);
      *(bf16x8*)(out + (size_t)(tok0 + row) * 384 + half * 192 + (colc << 3)) = vv;
    }
  }
}

// ---------------- GEMM: C[m][tok] = sum_k A[m][k] * Bt[tok][k] ----------------
// 128x128 tile, BK=64, dbuf LDS, counted vmcnt(8) pipeline w/ raw s_barrier,
// bijective XCD-chunk swizzle (m204) + y-fast decode.
// EPI 0: LDS-transpose -> bf16 outT[tok][ldo] @ ocol
// EPI 1: same + exact GELU (polynomial)
// EPI 2: swapped-operand acc -> float4 resid+store fp32 channel-major
template <int EPI>
__global__ __launch_bounds__(256, 2) void gemm_bt(const __bf16* __restrict__ A, int lda,
                                                  const __bf16* __restrict__ Bt, int ldb,
                                                  int K, int My,
                                                  __bf16* __restrict__ outT, int ldo, int ocol,
                                                  float* __restrict__ outR,
                                                  const float* __restrict__ resid,
                                                  int tok_off) {
  __shared__ __align__(16) char smem[65536];
  const int tid = threadIdx.x;
  const int lane = tid & 63;
  const int w = tid >> 6;
  const int wr = w >> 1, wc = w & 1;
  const int c = lane & 15, g = lane >> 4;

  const int nwg = gridDim.x;
  const int orig = blockIdx.x;
  const int q = nwg >> 3, r = nwg & 7;
  const int xcd = orig & 7, ii = orig >> 3;
  const int base = xcd < r ? xcd * (q + 1) : r * (q + 1) + (xcd - r) * q;
  const int wgid = base + ii;
  const int bx = wgid / My;
  const int by = wgid - bx * My;
  const int m0 = by << 7;
  const int n0 = bx << 7;

  const __bf16* ap[4];
  const __bf16* bp[4];
  #pragma unroll
  for (int i = 0; i < 4; ++i) {
    int s = (i << 8) + tid;
    int row = s >> 3;
    int kk = ((s ^ row) & 7) << 3;
    ap[i] = A  + (size_t)(m0 + row) * lda + kk;
    bp[i] = Bt + (size_t)(n0 + row) * ldb + kk;
  }
  auto stage = [&](int buf, int k0) {
    #pragma unroll
    for (int i = 0; i < 4; ++i) {
      gload_lds16(ap[i] + k0, smem + (buf << 15) + (((i << 8) + (w << 6)) << 4));
      gload_lds16(bp[i] + k0, smem + (buf << 15) + 16384 + (((i << 8) + (w << 6)) << 4));
    }
  };

  f32x4 acc[4][4] = {};
  const int nt = K >> 6;
  stage(0, 0);
  int cur = 0;
  for (int t = 0; t < nt; ++t) {
    if (t + 1 < nt) {
      stage(cur ^ 1, (t + 1) << 6);                      // keep 8 loads in flight
      asm volatile("s_waitcnt vmcnt(8)" ::: "memory");   // oldest 8 (tile t) landed
    } else {
      asm volatile("s_waitcnt vmcnt(0)" ::: "memory");
    }
    __builtin_amdgcn_s_barrier();
    __builtin_amdgcn_sched_barrier(0);
    const char* smA = smem + (cur << 15);
    const char* smB = smA + 16384;
    #pragma unroll
    for (int ks = 0; ks < 2; ++ks) {
      bf16x8 af[4], bfv[4];
      #pragma unroll
      for (int mi = 0; mi < 4; ++mi) {
        int r2 = (wr << 6) + (mi << 4) + c;
        af[mi] = *(const bf16x8*)(smA + (r2 << 7) + (((ks << 6) + (g << 4)) ^ ((r2 & 7) << 4)));
      }
      #pragma unroll
      for (int nj = 0; nj < 4; ++nj) {
        int r2 = (wc << 6) + (nj << 4) + c;
        bfv[nj] = *(const bf16x8*)(smB + (r2 << 7) + (((ks << 6) + (g << 4)) ^ ((r2 & 7) << 4)));
      }
      #pragma unroll
      for (int mi = 0; mi < 4; ++mi)
        #pragma unroll
        for (int nj = 0; nj < 4; ++nj) {
          if constexpr (EPI == 2)  // swapped: C rows = tokens
            acc[mi][nj] = __builtin_amdgcn_mfma_f32_16x16x32_bf16(bfv[nj], af[mi], acc[mi][nj], 0, 0, 0);
          else
            acc[mi][nj] = __builtin_amdgcn_mfma_f32_16x16x32_bf16(af[mi], bfv[nj], acc[mi][nj], 0, 0, 0);
        }
    }
    __builtin_amdgcn_s_barrier();
    cur ^= 1;
  }

  if constexpr (EPI <= 1) {
    #pragma unroll
    for (int mi = 0; mi < 4; ++mi)
      #pragma unroll
      for (int nj = 0; nj < 4; ++nj) {
        f32x4 v = acc[mi][nj];
        if constexpr (EPI == 1) {
          #pragma unroll
          for (int r2 = 0; r2 < 4; ++r2) v[r2] = gelu_f(v[r2]);
        }
        bf16x4 pk = {(__bf16)v[0], (__bf16)v[1], (__bf16)v[2], (__bf16)v[3]};
        int nl = (wc << 6) + (nj << 4) + c;
        int ml = (wr << 6) + (mi << 4) + (g << 2);
        *(bf16x4*)(smem + nl * 264 + ml * 2) = pk;
      }
    __syncthreads();
    #pragma unroll
    for (int it = 0; it < 8; ++it) {
      int id = (it << 8) + tid;
      int n = id >> 4, mc = id & 15;
      bf16x8 v = *(const bf16x8*)(smem + n * 264 + (mc << 4));
      *(bf16x8*)(outT + (size_t)(n0 + n) * ldo + (ocol + m0 + (mc << 3))) = v;
    }
  } else {
    #pragma unroll
    for (int nj = 0; nj < 4; ++nj) {
      int tokb = tok_off + n0 + (wc << 6) + (nj << 4) + (g << 2);
      unsigned bb = (unsigned)tokb / 784u;
      unsigned pp = (unsigned)tokb - bb * 784u;
      size_t base2 = (size_t)bb * (384u * 784u) + pp;
      #pragma unroll
      for (int mi = 0; mi < 4; ++mi) {
        int o = m0 + (wr << 6) + (mi << 4) + c;
        size_t a2 = base2 + (size_t)o * 784u;
        f32x4 rv = *(const f32x4*)(resid + a2);
        f32x4 v = acc[mi][nj] + rv;
        *(f32x4*)(outR + a2) = v;
      }
    }
  }
}

// ---------------- windowed attention: 1 wave per (window, head) ----------------
__global__ __launch_bounds__(256, 2) void attn_kernel(const __bf16* __restrict__ qkv,
                                                      const float* __restrict__ be,
                                                      __bf16* __restrict__ outt) {
  __shared__ __align__(16) char smem_all[4][16384];
  const int tid = threadIdx.x;
  const int lane = tid & 63;
  const int w = tid >> 6;
  char* sm = (char*)smem_all[w];
  const int pair = blockIdx.x * 4 + w;               // 6144 pairs
  const int h = pair % 6;
  const int wg = pair / 6;
  const int b = wg >> 4;
  const int wi = wg & 15;
  const int wh = wi >> 2, wwi = wi & 3;
  const int cc = lane & 15, g = lane >> 4;

  {
    int rsub = lane >> 3;
    int slot = lane & 7;
    int dc = (slot ^ rsub) << 3;
    #pragma unroll
    for (int i = 0; i < 8; ++i) {
      int r = i * 8 + rsub;
      int m = r < 49 ? r : 48;
      int im = div7u(m), jm = m - im * 7;
      int sh = wh * 7 + im + 3; if (sh >= 28) sh -= 28;
      int sw = wwi * 7 + jm + 3; if (sw >= 28) sw -= 28;
      size_t trow = (size_t)(b * 784 + sh * 28 + sw) * 1152;
      gload_lds16(qkv + trow + 384 + h * 64 + dc, sm + i * 1024);         // K
      gload_lds16(qkv + trow +       h * 64 + dc, sm + 8192 + i * 1024);  // Q
    }
  }
  asm volatile("s_waitcnt vmcnt(0)" ::: "memory");
  __syncthreads();

  f32x4 sacc[4][4] = {};
  #pragma unroll
  for (int ks = 0; ks < 2; ++ks) {
    bf16x8 kf[4], qf[4];
    #pragma unroll
    for (int mi = 0; mi < 4; ++mi) {
      int r = (mi << 4) + cc;
      kf[mi] = *(const bf16x8*)(sm + (r << 7) + (((ks << 6) + (g << 4)) ^ ((r & 7) << 4)));
    }
    #pragma unroll
    for (int nj = 0; nj < 4; ++nj) {
      int r = (nj << 4) + cc;
      qf[nj] = *(const bf16x8*)(sm + 8192 + (r << 7) + (((ks << 6) + (g << 4)) ^ ((r & 7) << 4)));
    }
    #pragma unroll
    for (int mi = 0; mi < 4; ++mi)
      #pragma unroll
      for (int nj = 0; nj < 4; ++nj)
        sacc[mi][nj] = __builtin_amdgcn_mfma_f32_16x16x32_bf16(kf[mi], qf[nj], sacc[mi][nj], 0, 0, 0);
  }
  __syncthreads();

  int r9m[4][4];
  #pragma unroll
  for (int mi = 0; mi < 4; ++mi)
    #pragma unroll
    for (int rr = 0; rr < 4; ++rr) {
      int m = (mi << 4) + (g << 2) + rr; if (m > 48) m = 48;
      int im = div7u(m), jm = m - im * 7;
      int sh = wh * 7 + im, sw = wwi * 7 + jm;
      r9m[mi][rr] = ((sh < 21) ? 0 : (sh < 25 ? 1 : 2)) * 3 + ((sw < 21) ? 0 : (sw < 25 ? 1 : 2));
    }

  #pragma unroll
  for (int nj = 0; nj < 4; ++nj) {
    int n = (nj << 4) + cc;
    int ncl = n > 48 ? 48 : n;
    int in_ = div7u(ncl), jn = ncl - in_ * 7;
    int shn = wh * 7 + in_, swn = wwi * 7 + jn;
    int r9n = ((shn < 21) ? 0 : (shn < 25 ? 1 : 2)) * 3 + ((swn < 21) ? 0 : (swn < 25 ? 1 : 2));
    float mx = -1e30f;
    #pragma unroll
    for (int mi = 0; mi < 4; ++mi) {
      f32x4 bia = *(const f32x4*)(be + (((h << 6) + n) << 6) + (mi << 4) + (g << 2));
      #pragma unroll
      for (int rr = 0; rr < 4; ++rr) {
        int m = (mi << 4) + (g << 2) + rr;
        float t = (m < 49)
            ? sacc[mi][nj][rr] * 0.125f + bia[rr] + ((r9m[mi][rr] == r9n) ? 0.f : -100.f)
            : -1e30f;
        sacc[mi][nj][rr] = t;
        mx = fmaxf(mx, t);
      }
    }
    mx = fmaxf(mx, __shfl_xor(mx, 16, 64));
    mx = fmaxf(mx, __shfl_xor(mx, 32, 64));
    float sum = 0.f;
    #pragma unroll
    for (int mi = 0; mi < 4; ++mi)
      #pragma unroll
      for (int rr = 0; rr < 4; ++rr) {
        float e = __expf(sacc[mi][nj][rr] - mx);
        sacc[mi][nj][rr] = e;
        sum += e;
      }
    sum += __shfl_xor(sum, 16, 64);
    sum += __shfl_xor(sum, 32, 64);
    float inv = __builtin_amdgcn_rcpf(sum);
    #pragma unroll
    for (int mi = 0; mi < 4; ++mi) {
      bf16x4 pk = {(__bf16)(sacc[mi][nj][0] * inv), (__bf16)(sacc[mi][nj][1] * inv),
                   (__bf16)(sacc[mi][nj][2] * inv), (__bf16)(sacc[mi][nj][3] * inv)};
      *(bf16x4*)(sm + 8192 + (n << 7) + (((mi << 5) + (g << 3)) ^ ((n & 7) << 4))) = pk;
    }
  }

  {
    int ml = lane & 15, dq = lane >> 4;
    #pragma unroll
    for (int it = 0; it < 4; ++it) {
      int m = (it << 4) + ml;
      int mc_ = m > 48 ? 48 : m;
      int im = div7u(mc_), jm = mc_ - im * 7;
      int sh = wh * 7 + im + 3; if (sh >= 28) sh -= 28;
      int sw = wwi * 7 + jm + 3; if (sw >= 28) sw -= 28;
      const __bf16* gv = qkv + (size_t)(b * 784 + sh * 28 + sw) * 1152 + 768 + h * 64;
      #pragma unroll
      for (int hd = 0; hd < 2; ++hd) {
        int dbase = (hd << 5) + (dq << 3);
        bf16x8 v = *(const bf16x8*)(gv + dbase);
        #pragma unroll
        for (int j = 0; j < 8; ++j) {
          int d = dbase + j;
          *(__bf16*)(sm + (d << 7) + ((((m >> 3) ^ (d & 7)) << 4) + ((m & 7) << 1))) = v[j];
        }
      }
    }
  }
  __syncthreads();

  f32x4 oacc[4][4] = {};
  #pragma unroll
  for (int ks = 0; ks < 2; ++ks) {
    bf16x8 pf[4], vf[4];
    #pragma unroll
    for (int ni = 0; ni < 4; ++ni) {
      int n = (ni << 4) + cc;
      pf[ni] = *(const bf16x8*)(sm + 8192 + (n << 7) + (((ks << 6) + (g << 4)) ^ ((n & 7) << 4)));
    }
    #pragma unroll
    for (int dj = 0; dj < 4; ++dj) {
      int d = (dj << 4) + cc;
      vf[dj] = *(const bf16x8*)(sm + (d << 7) + ((((ks << 2) + g) ^ (d & 7)) << 4));
    }
    #pragma unroll
    for (int ni = 0; ni < 4; ++ni)
      #pragma unroll
      for (int dj = 0; dj < 4; ++dj)
        oacc[ni][dj] = __builtin_amdgcn_mfma_f32_16x16x32_bf16(pf[ni], vf[dj], oacc[ni][dj], 0, 0, 0);
  }

  #pragma unroll
  for (int ni = 0; ni < 4; ++ni)
    #pragma unroll
    for (int rr = 0; rr < 4; ++rr) {
      int n = (ni << 4) + (g << 2) + rr;
      if (n < 49) {
        int im = div7u(n), jn = n - im * 7;
        int sh = wh * 7 + im + 3; if (sh >= 28) sh -= 28;
        int sw = wwi * 7 + jn + 3; if (sw >= 28) sw -= 28;
        __bf16* op = outt + (size_t)(b * 784 + sh * 28 + sw) * 384 + h * 64;
        #pragma unroll
        for (int dj = 0; dj < 4; ++dj)
          op[(dj << 4) + cc] = (__bf16)oacc[ni][dj][rr];
      }
    }
}

// ---------------- host launcher ----------------
extern "C" void kernel_launch(void* const* d_in, const int* in_sizes, int n_in,
                              void* d_out, int out_size, void* d_ws, size_t ws_size,
                              hipStream_t stream) {
  (void)in_sizes; (void)n_in; (void)out_size; (void)ws_size;
  const float* x     = (const float*)d_in[0];
  const float* n1w   = (const float*)d_in[1];
  const float* n1b   = (const float*)d_in[2];
  const float* qkvw  = (const float*)d_in[3];
  const float* tbl   = (const float*)d_in[4];
  const float* projw = (const float*)d_in[5];
  const float* n2w   = (const float*)d_in[6];
  const float* n2b   = (const float*)d_in[7];
  const float* w1    = (const float*)d_in[8];
  const float* w3    = (const float*)d_in[9];
  float* out = (float*)d_out;

  char* ws = (char*)d_ws;
  __bf16* bufA = (__bf16*)ws;                               // 38,535,168 B
  __bf16* bufB = (__bf16*)(ws + 38535168);                  // 115,605,504 B
  float*  be   = (float*)(ws + 154140672);                  // 98,304 B
  __bf16* wq   = (__bf16*)(ws + 154238976);
  __bf16* wp   = wq + 442368;
  __bf16* wm1  = wp + 147456;
  __bf16* wm3  = wm1 + 589824;

  cvt_all_kernel<<<6912, 256, 0, stream>>>(qkvw, projw, w1, w3, wq, wp, wm1, wm3);
  bias_expand_kernel<<<96, 256, 0, stream>>>(tbl, be);

  // LN1 -> xn_t (bufA)
  ln_t_kernel<<<784, 256, 0, stream>>>(x, n1w, n1b, bufA);
  // qkv: [1152x384] @ xn_t -> qkv_t (bufB, token-major)
  gemm_bt<0><<<392 * 9, 256, 0, stream>>>(wq, 384, bufA, 384, 384, 9, bufB, 1152, 0,
                                          nullptr, nullptr, 0);
  // attention -> attn_out_t (bufA)
  attn_kernel<<<1536, 256, 0, stream>>>(bufB, be, bufA);
  // proj + residual(x) -> d_out (fp32 channel-major)
  gemm_bt<2><<<392 * 3, 256, 0, stream>>>(wp, 384, bufA, 384, 384, 3, nullptr, 0, 0,
                                          out, x, 0);
  // LN2 -> xn2_t (bufA)
  ln_t_kernel<<<784, 256, 0, stream>>>(out, n2w, n2b, bufA);
  // MLP, token-split halves: full HID=1536 per half; h-half [25088][1536] in bufB
  for (int hh = 0; hh < 2; ++hh) {
    const int toff = hh * 25088;
    gemm_bt<1><<<196 * 12, 256, 0, stream>>>(wm1, 384, bufA + (size_t)toff * 384, 384, 384, 12,
                                             bufB, 1536, 0, nullptr, nullptr, 0);
    gemm_bt<2><<<196 * 3, 256, 0, stream>>>(wm3, 1536, bufB, 1536, 1536, 3,
                                            nullptr, 0, 0, out, out, toff);
  }
}